// Round 1
// baseline (747.773 us; speedup 1.0000x reference)
//
#include <hip/hip_runtime.h>

#define N_TOK    8192
#define D_DIM    1024
#define F_DIM    1024
#define NESH     9          // 8 routed experts + shared as expert 8
#define MAX_ROWS 25600      // worst-case padded routed (17408) + shared (8192)
#define BM 128
#define BN 128
#define BK 64

// meta layout (ints)
#define MC 0    // cnt[8]
#define MF 8    // fill[8]
#define MO 16   // off_e[9]
#define MT 25   // total rows

typedef float  f4    __attribute__((ext_vector_type(4)));
typedef float  f32x4 __attribute__((ext_vector_type(4)));
typedef short  s16x8 __attribute__((ext_vector_type(8)));
typedef unsigned short u16x8 __attribute__((ext_vector_type(8)));

static __device__ __forceinline__ unsigned short f2bf(float f) {
    union { float f; unsigned u; } v; v.f = f;
    unsigned r = v.u + 0x7FFFu + ((v.u >> 16) & 1u);
    return (unsigned short)(r >> 16);
}

#define GLDS(gp, lp) __builtin_amdgcn_global_load_lds( \
    (const __attribute__((address_space(1))) void*)(gp), \
    (__attribute__((address_space(3))) void*)(lp), 16, 0, 0)

// ---------------------------------------------------------------- convert x
__global__ __launch_bounds__(256) void k_convert_x(
    const float* __restrict__ x, unsigned short* __restrict__ xb)
{
    int g = blockIdx.x * 256 + threadIdx.x;       // N*D/8 groups
    const f4* xs = (const f4*)x;
    f4 a = xs[2*g], b = xs[2*g+1];
    u16x8 o;
    o[0]=f2bf(a[0]); o[1]=f2bf(a[1]); o[2]=f2bf(a[2]); o[3]=f2bf(a[3]);
    o[4]=f2bf(b[0]); o[5]=f2bf(b[1]); o[6]=f2bf(b[2]); o[7]=f2bf(b[3]);
    *(u16x8*)&xb[8*(size_t)g] = o;
}

// ------------------------------------------- transpose+convert 27 matrices
// dest[r][c] = src[c][r], all 1024x1024, f32 -> bf16
__global__ __launch_bounds__(256) void k_transpose(
    const float* __restrict__ wg, const float* __restrict__ wu,
    const float* __restrict__ wd, const float* __restrict__ sg,
    const float* __restrict__ su, const float* __restrict__ sd,
    unsigned short* __restrict__ wgt, unsigned short* __restrict__ wut,
    unsigned short* __restrict__ wdt)
{
    int bx = blockIdx.x;
    int m = bx >> 8;                // 0..26
    int tile = bx & 255;
    int ty = tile >> 4, tx = tile & 15;
    int set = m / 9, e = m % 9;
    const float* src; unsigned short* dst;
    if (set == 0)      { src = (e < 8) ? wg + (size_t)e*1048576 : sg; dst = wgt + (size_t)e*1048576; }
    else if (set == 1) { src = (e < 8) ? wu + (size_t)e*1048576 : su; dst = wut + (size_t)e*1048576; }
    else               { src = (e < 8) ? wd + (size_t)e*1048576 : sd; dst = wdt + (size_t)e*1048576; }

    __shared__ __align__(16) unsigned short ts[64 * 80];
    int t = threadIdx.x;
    int rT0 = ty * 64, cT0 = tx * 64;
    #pragma unroll
    for (int i = 0; i < 16; i++) {
        int lin = t + i * 256;
        int mr = lin >> 6, mc = lin & 63;
        float v = src[(size_t)(cT0 + mr) * 1024 + rT0 + mc];
        ts[mc * 80 + mr] = f2bf(v);
    }
    __syncthreads();
    #pragma unroll
    for (int i = 0; i < 2; i++) {
        int r = (t >> 3) + i * 32;
        int c0 = (t & 7) * 8;
        *(u16x8*)&dst[(size_t)(rT0 + r) * 1024 + cT0 + c0] = *(u16x8*)&ts[r * 80 + c0];
    }
}

// ---------------------------------------------------------------- router
__global__ __launch_bounds__(256) void k_router(
    const float* __restrict__ x, const float* __restrict__ rw,
    int* __restrict__ tk_i, float* __restrict__ tk_w, int* __restrict__ meta)
{
    int wid = threadIdx.x >> 6, lane = threadIdx.x & 63;
    int n = blockIdx.x * 4 + wid;
    const float* xr = x + (size_t)n * D_DIM;
    float acc[8] = {0,0,0,0,0,0,0,0};
    #pragma unroll
    for (int it = 0; it < 16; it++) {
        int d = it * 64 + lane;
        float xv = xr[d];
        f4 r0 = *(const f4*)(rw + (size_t)d * 8);
        f4 r1 = *(const f4*)(rw + (size_t)d * 8 + 4);
        acc[0] += xv * r0[0]; acc[1] += xv * r0[1]; acc[2] += xv * r0[2]; acc[3] += xv * r0[3];
        acc[4] += xv * r1[0]; acc[5] += xv * r1[1]; acc[6] += xv * r1[2]; acc[7] += xv * r1[3];
    }
    #pragma unroll
    for (int e = 0; e < 8; e++)
        for (int off = 32; off; off >>= 1)
            acc[e] += __shfl_xor(acc[e], off, 64);
    if (lane == 0) {
        float mx = acc[0];
        for (int e = 1; e < 8; e++) mx = fmaxf(mx, acc[e]);
        float p[8], s = 0.f;
        for (int e = 0; e < 8; e++) { p[e] = expf(acc[e] - mx); s += p[e]; }
        int i0 = 0;
        for (int e = 1; e < 8; e++) if (p[e] > p[i0]) i0 = e;
        int i1 = (i0 == 0) ? 1 : 0;
        for (int e = 0; e < 8; e++) if (e != i0 && p[e] > p[i1]) i1 = e;
        float p0 = p[i0] / s, p1 = p[i1] / s;
        float rs = p0 + p1 + 1e-9f;
        tk_i[2*n] = i0;  tk_i[2*n+1] = i1;
        tk_w[2*n] = p0 / rs;  tk_w[2*n+1] = p1 / rs;
        atomicAdd(&meta[MC + i0], 1);
        atomicAdd(&meta[MC + i1], 1);
    }
}

__global__ void k_offsets(int* __restrict__ meta)
{
    if (threadIdx.x == 0) {
        int acc = 0;
        for (int e = 0; e < 8; e++) {
            meta[MO + e] = acc;
            acc += ((meta[MC + e] + 127) >> 7) << 7;
        }
        meta[MO + 8] = acc;          // shared region start (mult of 128)
        meta[MT] = acc + N_TOK;      // total rows
    }
}

__global__ __launch_bounds__(256) void k_prefill(
    int* __restrict__ row_token, int* __restrict__ row_expert, float* __restrict__ row_weight)
{
    int i = blockIdx.x * 256 + threadIdx.x;
    row_token[i] = -1; row_expert[i] = 0; row_weight[i] = 0.f;
}

__global__ __launch_bounds__(256) void k_scatter(
    const int* __restrict__ tk_i, const float* __restrict__ tk_w, int* __restrict__ meta,
    int* __restrict__ row_token, int* __restrict__ row_expert, float* __restrict__ row_weight)
{
    int n = blockIdx.x * 256 + threadIdx.x;
    #pragma unroll
    for (int k = 0; k < 2; k++) {
        int e = tk_i[2*n + k];
        float w = tk_w[2*n + k];
        int pos = meta[MO + e] + atomicAdd(&meta[MF + e], 1);
        row_token[pos] = n; row_expert[pos] = e; row_weight[pos] = w;
    }
    int pos = meta[MO + 8] + n;
    row_token[pos] = n; row_expert[pos] = 8; row_weight[pos] = 1.f;
}

// ----------------------------------------------- GEMM1: gate+up, silu*mul -> h
__global__ __launch_bounds__(256) void k_gemm1(
    const unsigned short* __restrict__ xb,
    const unsigned short* __restrict__ wgt,
    const unsigned short* __restrict__ wut,
    const int* __restrict__ row_token,
    const int* __restrict__ row_expert,
    const int* __restrict__ meta,
    unsigned short* __restrict__ h)
{
    const int total = meta[MT];
    const int rt = blockIdx.x >> 3, ct = blockIdx.x & 7;
    const int row0 = rt * BM;
    if (row0 >= total) return;
    const int e = row_expert[row0];

    __shared__ __align__(16) unsigned short As[BM * BK];
    __shared__ __align__(16) unsigned short Bg[BN * BK];
    __shared__ __align__(16) unsigned short Bu[BN * BK];

    const int t = threadIdx.x;
    const int lane = t & 63;
    const int wm = t >> 7, wn = (t >> 6) & 1;

    const unsigned short* asrc[4];
    #pragma unroll
    for (int i = 0; i < 4; i++) {
        int slot = t + i * 256;
        int tok = row_token[row0 + (slot >> 3)];
        if (tok < 0) tok = 0;
        asrc[i] = xb + (size_t)tok * D_DIM + (slot & 7) * 8;
    }
    const unsigned short* bg0 = wgt + ((size_t)e * F_DIM + ct * BN) * D_DIM;
    const unsigned short* bu0 = wut + ((size_t)e * F_DIM + ct * BN) * D_DIM;

    f32x4 accg[4][4] = {}, accu[4][4] = {};

    for (int k0 = 0; k0 < D_DIM; k0 += BK) {
        #pragma unroll
        for (int i = 0; i < 4; i++) {
            int slot = t + i * 256;
            GLDS(asrc[i] + k0, &As[slot * 8]);
        }
        #pragma unroll
        for (int i = 0; i < 4; i++) {
            int slot = t + i * 256;
            size_t boff = (size_t)(slot >> 3) * D_DIM + k0 + (slot & 7) * 8;
            GLDS(bg0 + boff, &Bg[slot * 8]);
            GLDS(bu0 + boff, &Bu[slot * 8]);
        }
        __syncthreads();
        #pragma unroll
        for (int kk = 0; kk < BK; kk += 32) {
            const int koff = kk + (lane >> 4) * 8;
            s16x8 a[4], bg[4], bu[4];
            #pragma unroll
            for (int m = 0; m < 4; m++)
                a[m] = *(const s16x8*)&As[(wm * 64 + m * 16 + (lane & 15)) * BK + koff];
            #pragma unroll
            for (int n = 0; n < 4; n++) {
                bg[n] = *(const s16x8*)&Bg[(wn * 64 + n * 16 + (lane & 15)) * BK + koff];
                bu[n] = *(const s16x8*)&Bu[(wn * 64 + n * 16 + (lane & 15)) * BK + koff];
            }
            #pragma unroll
            for (int m = 0; m < 4; m++)
                #pragma unroll
                for (int n = 0; n < 4; n++) {
                    accg[m][n] = __builtin_amdgcn_mfma_f32_16x16x32_bf16(a[m], bg[n], accg[m][n], 0, 0, 0);
                    accu[m][n] = __builtin_amdgcn_mfma_f32_16x16x32_bf16(a[m], bu[n], accu[m][n], 0, 0, 0);
                }
        }
        __syncthreads();
    }

    #pragma unroll
    for (int m = 0; m < 4; m++)
        #pragma unroll
        for (int r = 0; r < 4; r++) {
            int grow = row0 + wm * 64 + m * 16 + (lane >> 4) * 4 + r;
            unsigned short* hrow = h + (size_t)grow * F_DIM + ct * BN + wn * 64 + (lane & 15);
            #pragma unroll
            for (int n = 0; n < 4; n++) {
                float g = accg[m][n][r], u = accu[m][n][r];
                float sv = g / (1.f + __expf(-g));
                hrow[n * 16] = f2bf(sv * u);
            }
        }
}

// ----------------------------------------------- GEMM2: down + weighted add
__global__ __launch_bounds__(256) void k_gemm2(
    const unsigned short* __restrict__ h,
    const unsigned short* __restrict__ wdt,
    const int* __restrict__ row_token,
    const float* __restrict__ row_weight,
    const int* __restrict__ row_expert,
    const int* __restrict__ meta,
    float* __restrict__ out)
{
    const int total = meta[MT];
    const int rt = blockIdx.x >> 3, ct = blockIdx.x & 7;
    const int row0 = rt * BM;
    if (row0 >= total) return;
    const int e = row_expert[row0];

    __shared__ __align__(16) unsigned short As[BM * BK];
    __shared__ __align__(16) unsigned short Bs[BN * BK];

    const int t = threadIdx.x;
    const int lane = t & 63;
    const int wm = t >> 7, wn = (t >> 6) & 1;

    const unsigned short* b0 = wdt + ((size_t)e * D_DIM + ct * BN) * F_DIM;

    f32x4 acc[4][4] = {};

    for (int k0 = 0; k0 < F_DIM; k0 += BK) {
        #pragma unroll
        for (int i = 0; i < 4; i++) {
            int slot = t + i * 256;
            size_t aoff = (size_t)(row0 + (slot >> 3)) * F_DIM + k0 + (slot & 7) * 8;
            size_t boff = (size_t)(slot >> 3) * F_DIM + k0 + (slot & 7) * 8;
            GLDS(h + aoff, &As[slot * 8]);
            GLDS(b0 + boff, &Bs[slot * 8]);
        }
        __syncthreads();
        #pragma unroll
        for (int kk = 0; kk < BK; kk += 32) {
            const int koff = kk + (lane >> 4) * 8;
            s16x8 a[4], b[4];
            #pragma unroll
            for (int m = 0; m < 4; m++)
                a[m] = *(const s16x8*)&As[(wm * 64 + m * 16 + (lane & 15)) * BK + koff];
            #pragma unroll
            for (int n = 0; n < 4; n++)
                b[n] = *(const s16x8*)&Bs[(wn * 64 + n * 16 + (lane & 15)) * BK + koff];
            #pragma unroll
            for (int m = 0; m < 4; m++)
                #pragma unroll
                for (int n = 0; n < 4; n++)
                    acc[m][n] = __builtin_amdgcn_mfma_f32_16x16x32_bf16(a[m], b[n], acc[m][n], 0, 0, 0);
        }
        __syncthreads();
    }

    #pragma unroll
    for (int m = 0; m < 4; m++)
        #pragma unroll
        for (int r = 0; r < 4; r++) {
            int grow = row0 + wm * 64 + m * 16 + (lane >> 4) * 4 + r;
            int tok = row_token[grow];
            if (tok < 0) continue;
            float w = row_weight[grow];
            float* orow = out + (size_t)tok * D_DIM + ct * BN + wn * 64 + (lane & 15);
            #pragma unroll
            for (int n = 0; n < 4; n++)
                atomicAdd(&orow[n * 16], w * acc[m][n][r]);
        }
}

// ---------------------------------------------------------------- launch
extern "C" void kernel_launch(void* const* d_in, const int* in_sizes, int n_in,
                              void* d_out, int out_size, void* d_ws, size_t ws_size,
                              hipStream_t stream)
{
    const float* x  = (const float*)d_in[0];
    const float* rw = (const float*)d_in[1];
    const float* sg = (const float*)d_in[2];
    const float* su = (const float*)d_in[3];
    const float* sd = (const float*)d_in[4];
    const float* wg = (const float*)d_in[5];
    const float* wu = (const float*)d_in[6];
    const float* wd = (const float*)d_in[7];
    float* out = (float*)d_out;

    char* p = (char*)d_ws;
    unsigned short* xb  = (unsigned short*)p; p += (size_t)N_TOK * D_DIM * 2;
    unsigned short* wgt = (unsigned short*)p; p += (size_t)NESH * D_DIM * F_DIM * 2;
    unsigned short* wut = (unsigned short*)p; p += (size_t)NESH * D_DIM * F_DIM * 2;
    unsigned short* wdt = (unsigned short*)p; p += (size_t)NESH * D_DIM * F_DIM * 2;
    unsigned short* h   = (unsigned short*)p; p += (size_t)MAX_ROWS * F_DIM * 2;
    int*   row_token  = (int*)p;   p += (size_t)MAX_ROWS * 4;
    int*   row_expert = (int*)p;   p += (size_t)MAX_ROWS * 4;
    float* row_weight = (float*)p; p += (size_t)MAX_ROWS * 4;
    int*   tk_i = (int*)p;         p += (size_t)N_TOK * 2 * 4;
    float* tk_w = (float*)p;       p += (size_t)N_TOK * 2 * 4;
    int*   meta = (int*)p;         p += 1024;
    if ((size_t)(p - (char*)d_ws) > ws_size) return;

    hipMemsetAsync(out, 0, (size_t)N_TOK * D_DIM * 4, stream);
    hipMemsetAsync(meta, 0, 256, stream);

    k_convert_x<<<N_TOK * D_DIM / 8 / 256, 256, 0, stream>>>(x, xb);
    k_transpose<<<27 * 256, 256, 0, stream>>>(wg, wu, wd, sg, su, sd, wgt, wut, wdt);
    k_router<<<N_TOK / 4, 256, 0, stream>>>(x, rw, tk_i, tk_w, meta);
    k_offsets<<<1, 64, 0, stream>>>(meta);
    k_prefill<<<MAX_ROWS / 256, 256, 0, stream>>>(row_token, row_expert, row_weight);
    k_scatter<<<N_TOK / 256, 256, 0, stream>>>(tk_i, tk_w, meta, row_token, row_expert, row_weight);
    k_gemm1<<<(MAX_ROWS / BM) * 8, 256, 0, stream>>>(xb, wgt, wut, row_token, row_expert, meta, h);
    k_gemm2<<<(MAX_ROWS / BM) * 8, 256, 0, stream>>>(h, wdt, row_token, row_weight, row_expert, meta, out);
}

// Round 2
// 695.717 us; speedup vs baseline: 1.0748x; 1.0748x over previous
//
#include <hip/hip_runtime.h>

#define N_TOK    8192
#define D_DIM    1024
#define F_DIM    1024
#define NESH     9          // 8 routed experts + shared as expert 8
#define MAX_ROWS 25600      // worst-case padded routed (17408) + shared (8192)
#define BM 128
#define BN 128
#define BK 64

// meta layout (ints)
#define MC 0    // cnt[8]
#define MF 8    // fill[8]
#define MO 16   // off_e[9]
#define MT 25   // total rows

typedef float  f4    __attribute__((ext_vector_type(4)));
typedef float  f32x4 __attribute__((ext_vector_type(4)));
typedef short  s16x8 __attribute__((ext_vector_type(8)));
typedef unsigned short u16x8 __attribute__((ext_vector_type(8)));

static __device__ __forceinline__ unsigned short f2bf(float f) {
    union { float f; unsigned u; } v; v.f = f;
    unsigned r = v.u + 0x7FFFu + ((v.u >> 16) & 1u);
    return (unsigned short)(r >> 16);
}

#define GLDS(gp, lp) __builtin_amdgcn_global_load_lds( \
    (const __attribute__((address_space(1))) void*)(gp), \
    (__attribute__((address_space(3))) void*)(lp), 16, 0, 0)

// LDS XOR swizzle (T2): byte ^= ((row&7)<<4)  -> bf16-index ^= ((row&7)<<3)
#define RSWZ(row, idx) ((idx) ^ (((row) & 7) << 3))

// ---------------------------------------------------------------- convert x
__global__ __launch_bounds__(256) void k_convert_x(
    const float* __restrict__ x, unsigned short* __restrict__ xb)
{
    int g = blockIdx.x * 256 + threadIdx.x;       // N*D/8 groups
    const f4* xs = (const f4*)x;
    f4 a = xs[2*g], b = xs[2*g+1];
    u16x8 o;
    o[0]=f2bf(a[0]); o[1]=f2bf(a[1]); o[2]=f2bf(a[2]); o[3]=f2bf(a[3]);
    o[4]=f2bf(b[0]); o[5]=f2bf(b[1]); o[6]=f2bf(b[2]); o[7]=f2bf(b[3]);
    *(u16x8*)&xb[8*(size_t)g] = o;
}

// ------------------------------------------- transpose+convert 27 matrices
__global__ __launch_bounds__(256) void k_transpose(
    const float* __restrict__ wg, const float* __restrict__ wu,
    const float* __restrict__ wd, const float* __restrict__ sg,
    const float* __restrict__ su, const float* __restrict__ sd,
    unsigned short* __restrict__ wgt, unsigned short* __restrict__ wut,
    unsigned short* __restrict__ wdt)
{
    int bx = blockIdx.x;
    int m = bx >> 8;                // 0..26
    int tile = bx & 255;
    int ty = tile >> 4, tx = tile & 15;
    int set = m / 9, e = m % 9;
    const float* src; unsigned short* dst;
    if (set == 0)      { src = (e < 8) ? wg + (size_t)e*1048576 : sg; dst = wgt + (size_t)e*1048576; }
    else if (set == 1) { src = (e < 8) ? wu + (size_t)e*1048576 : su; dst = wut + (size_t)e*1048576; }
    else               { src = (e < 8) ? wd + (size_t)e*1048576 : sd; dst = wdt + (size_t)e*1048576; }

    __shared__ __align__(16) unsigned short ts[64 * 80];
    int t = threadIdx.x;
    int rT0 = ty * 64, cT0 = tx * 64;
    #pragma unroll
    for (int i = 0; i < 16; i++) {
        int lin = t + i * 256;
        int mr = lin >> 6, mc = lin & 63;
        float v = src[(size_t)(cT0 + mr) * 1024 + rT0 + mc];
        ts[mc * 80 + mr] = f2bf(v);
    }
    __syncthreads();
    #pragma unroll
    for (int i = 0; i < 2; i++) {
        int r = (t >> 3) + i * 32;
        int c0 = (t & 7) * 8;
        *(u16x8*)&dst[(size_t)(rT0 + r) * 1024 + cT0 + c0] = *(u16x8*)&ts[r * 80 + c0];
    }
}

// ---------------------------------------------------------------- router
__global__ __launch_bounds__(256) void k_router(
    const float* __restrict__ x, const float* __restrict__ rw,
    int* __restrict__ tk_i, float* __restrict__ tk_w, int* __restrict__ meta)
{
    int wid = threadIdx.x >> 6, lane = threadIdx.x & 63;
    int n = blockIdx.x * 4 + wid;
    const float* xr = x + (size_t)n * D_DIM;
    float acc[8] = {0,0,0,0,0,0,0,0};
    #pragma unroll
    for (int it = 0; it < 16; it++) {
        int d = it * 64 + lane;
        float xv = xr[d];
        f4 r0 = *(const f4*)(rw + (size_t)d * 8);
        f4 r1 = *(const f4*)(rw + (size_t)d * 8 + 4);
        acc[0] += xv * r0[0]; acc[1] += xv * r0[1]; acc[2] += xv * r0[2]; acc[3] += xv * r0[3];
        acc[4] += xv * r1[0]; acc[5] += xv * r1[1]; acc[6] += xv * r1[2]; acc[7] += xv * r1[3];
    }
    #pragma unroll
    for (int e = 0; e < 8; e++)
        for (int off = 32; off; off >>= 1)
            acc[e] += __shfl_xor(acc[e], off, 64);
    if (lane == 0) {
        float mx = acc[0];
        for (int e = 1; e < 8; e++) mx = fmaxf(mx, acc[e]);
        float p[8], s = 0.f;
        for (int e = 0; e < 8; e++) { p[e] = expf(acc[e] - mx); s += p[e]; }
        int i0 = 0;
        for (int e = 1; e < 8; e++) if (p[e] > p[i0]) i0 = e;
        int i1 = (i0 == 0) ? 1 : 0;
        for (int e = 0; e < 8; e++) if (e != i0 && p[e] > p[i1]) i1 = e;
        float p0 = p[i0] / s, p1 = p[i1] / s;
        float rs = p0 + p1 + 1e-9f;
        tk_i[2*n] = i0;  tk_i[2*n+1] = i1;
        tk_w[2*n] = p0 / rs;  tk_w[2*n+1] = p1 / rs;
        atomicAdd(&meta[MC + i0], 1);
        atomicAdd(&meta[MC + i1], 1);
    }
}

__global__ void k_offsets(int* __restrict__ meta)
{
    if (threadIdx.x == 0) {
        int acc = 0;
        for (int e = 0; e < 8; e++) {
            meta[MO + e] = acc;
            acc += ((meta[MC + e] + 127) >> 7) << 7;
        }
        meta[MO + 8] = acc;          // shared region start (mult of 128)
        meta[MT] = acc + N_TOK;      // total rows
    }
}

__global__ __launch_bounds__(256) void k_prefill(
    int* __restrict__ row_token, int* __restrict__ row_expert, float* __restrict__ row_weight)
{
    int i = blockIdx.x * 256 + threadIdx.x;
    row_token[i] = -1; row_expert[i] = 0; row_weight[i] = 0.f;
}

__global__ __launch_bounds__(256) void k_scatter(
    const int* __restrict__ tk_i, const float* __restrict__ tk_w, int* __restrict__ meta,
    int* __restrict__ row_token, int* __restrict__ row_expert, float* __restrict__ row_weight)
{
    int n = blockIdx.x * 256 + threadIdx.x;
    #pragma unroll
    for (int k = 0; k < 2; k++) {
        int e = tk_i[2*n + k];
        float w = tk_w[2*n + k];
        int pos = meta[MO + e] + atomicAdd(&meta[MF + e], 1);
        row_token[pos] = n; row_expert[pos] = e; row_weight[pos] = w;
    }
    int pos = meta[MO + 8] + n;
    row_token[pos] = n; row_expert[pos] = 8; row_weight[pos] = 1.f;
}

// ----------------------------------------------- GEMM1: gate+up, silu*mul -> h
__global__ __launch_bounds__(256) void k_gemm1(
    const unsigned short* __restrict__ xb,
    const unsigned short* __restrict__ wgt,
    const unsigned short* __restrict__ wut,
    const int* __restrict__ row_token,
    const int* __restrict__ row_expert,
    const int* __restrict__ meta,
    unsigned short* __restrict__ h)
{
    const int total = meta[MT];
    const int rt = blockIdx.x >> 3, ct = blockIdx.x & 7;
    const int row0 = rt * BM;
    if (row0 >= total) return;
    const int e = row_expert[row0];

    __shared__ __align__(16) unsigned short As[BM * BK];
    __shared__ __align__(16) unsigned short Bg[BN * BK];
    __shared__ __align__(16) unsigned short Bu[BN * BK];

    const int t = threadIdx.x;
    const int lane = t & 63;
    const int wm = t >> 7, wn = (t >> 6) & 1;

    // staging geometry: slot -> (row = slot>>3, chunk cg = slot&7 of 16B)
    // source chunk pre-swizzled: scg = cg ^ (row&7); LDS dest stays linear.
    const unsigned short* asrc[4];
    int srow[4], scg[4];
    #pragma unroll
    for (int i = 0; i < 4; i++) {
        int slot = t + i * 256;
        srow[i] = slot >> 3;
        scg[i]  = (slot & 7) ^ (srow[i] & 7);
        int tok = row_token[row0 + srow[i]];
        if (tok < 0) tok = 0;
        asrc[i] = xb + (size_t)tok * D_DIM + scg[i] * 8;
    }
    const unsigned short* bg0 = wgt + ((size_t)e * F_DIM + ct * BN) * D_DIM;
    const unsigned short* bu0 = wut + ((size_t)e * F_DIM + ct * BN) * D_DIM;

    f32x4 accg[4][4] = {}, accu[4][4] = {};

    for (int k0 = 0; k0 < D_DIM; k0 += BK) {
        #pragma unroll
        for (int i = 0; i < 4; i++) {
            int slot = t + i * 256;
            GLDS(asrc[i] + k0, &As[slot * 8]);
        }
        #pragma unroll
        for (int i = 0; i < 4; i++) {
            int slot = t + i * 256;
            size_t boff = (size_t)srow[i] * D_DIM + k0 + scg[i] * 8;
            GLDS(bg0 + boff, &Bg[slot * 8]);
            GLDS(bu0 + boff, &Bu[slot * 8]);
        }
        __syncthreads();
        #pragma unroll
        for (int kk = 0; kk < BK; kk += 32) {
            const int koff = kk + (lane >> 4) * 8;
            s16x8 a[4], bg[4], bu[4];
            #pragma unroll
            for (int m = 0; m < 4; m++) {
                int row = wm * 64 + m * 16 + (lane & 15);
                a[m] = *(const s16x8*)&As[RSWZ(row, row * BK + koff)];
            }
            #pragma unroll
            for (int n = 0; n < 4; n++) {
                int row = wn * 64 + n * 16 + (lane & 15);
                bg[n] = *(const s16x8*)&Bg[RSWZ(row, row * BK + koff)];
                bu[n] = *(const s16x8*)&Bu[RSWZ(row, row * BK + koff)];
            }
            #pragma unroll
            for (int m = 0; m < 4; m++)
                #pragma unroll
                for (int n = 0; n < 4; n++) {
                    accg[m][n] = __builtin_amdgcn_mfma_f32_16x16x32_bf16(a[m], bg[n], accg[m][n], 0, 0, 0);
                    accu[m][n] = __builtin_amdgcn_mfma_f32_16x16x32_bf16(a[m], bu[n], accu[m][n], 0, 0, 0);
                }
        }
        __syncthreads();
    }

    #pragma unroll
    for (int m = 0; m < 4; m++)
        #pragma unroll
        for (int r = 0; r < 4; r++) {
            int grow = row0 + wm * 64 + m * 16 + (lane >> 4) * 4 + r;
            unsigned short* hrow = h + (size_t)grow * F_DIM + ct * BN + wn * 64 + (lane & 15);
            #pragma unroll
            for (int n = 0; n < 4; n++) {
                float g = accg[m][n][r], u = accu[m][n][r];
                float sv = g / (1.f + __expf(-g));
                hrow[n * 16] = f2bf(sv * u);
            }
        }
}

// ----------------------------------------------- GEMM2: down + weighted add
__global__ __launch_bounds__(256) void k_gemm2(
    const unsigned short* __restrict__ h,
    const unsigned short* __restrict__ wdt,
    const int* __restrict__ row_token,
    const float* __restrict__ row_weight,
    const int* __restrict__ row_expert,
    const int* __restrict__ meta,
    float* __restrict__ out)
{
    const int total = meta[MT];
    const int rt = blockIdx.x >> 3, ct = blockIdx.x & 7;
    const int row0 = rt * BM;
    if (row0 >= total) return;
    const int e = row_expert[row0];

    __shared__ __align__(16) unsigned short As[BM * BK];
    __shared__ __align__(16) unsigned short Bs[BN * BK];

    const int t = threadIdx.x;
    const int lane = t & 63;
    const int wm = t >> 7, wn = (t >> 6) & 1;

    const unsigned short* b0 = wdt + ((size_t)e * D_DIM + ct * BN) * F_DIM;

    f32x4 acc[4][4] = {};

    for (int k0 = 0; k0 < F_DIM; k0 += BK) {
        #pragma unroll
        for (int i = 0; i < 4; i++) {
            int slot = t + i * 256;
            int row = slot >> 3;
            int cg  = (slot & 7) ^ (row & 7);
            size_t aoff = (size_t)(row0 + row) * F_DIM + k0 + cg * 8;
            size_t boff = (size_t)row * F_DIM + k0 + cg * 8;
            GLDS(h + aoff, &As[slot * 8]);
            GLDS(b0 + boff, &Bs[slot * 8]);
        }
        __syncthreads();
        #pragma unroll
        for (int kk = 0; kk < BK; kk += 32) {
            const int koff = kk + (lane >> 4) * 8;
            s16x8 a[4], b[4];
            #pragma unroll
            for (int m = 0; m < 4; m++) {
                int row = wm * 64 + m * 16 + (lane & 15);
                a[m] = *(const s16x8*)&As[RSWZ(row, row * BK + koff)];
            }
            #pragma unroll
            for (int n = 0; n < 4; n++) {
                int row = wn * 64 + n * 16 + (lane & 15);
                b[n] = *(const s16x8*)&Bs[RSWZ(row, row * BK + koff)];
            }
            #pragma unroll
            for (int m = 0; m < 4; m++)
                #pragma unroll
                for (int n = 0; n < 4; n++)
                    acc[m][n] = __builtin_amdgcn_mfma_f32_16x16x32_bf16(a[m], b[n], acc[m][n], 0, 0, 0);
        }
        __syncthreads();
    }

    #pragma unroll
    for (int m = 0; m < 4; m++)
        #pragma unroll
        for (int r = 0; r < 4; r++) {
            int grow = row0 + wm * 64 + m * 16 + (lane >> 4) * 4 + r;
            int tok = row_token[grow];
            if (tok < 0) continue;
            float w = row_weight[grow];
            float* orow = out + (size_t)tok * D_DIM + ct * BN + wn * 64 + (lane & 15);
            #pragma unroll
            for (int n = 0; n < 4; n++)
                atomicAdd(&orow[n * 16], w * acc[m][n][r]);
        }
}

// ---------------------------------------------------------------- launch
extern "C" void kernel_launch(void* const* d_in, const int* in_sizes, int n_in,
                              void* d_out, int out_size, void* d_ws, size_t ws_size,
                              hipStream_t stream)
{
    const float* x  = (const float*)d_in[0];
    const float* rw = (const float*)d_in[1];
    const float* sg = (const float*)d_in[2];
    const float* su = (const float*)d_in[3];
    const float* sd = (const float*)d_in[4];
    const float* wg = (const float*)d_in[5];
    const float* wu = (const float*)d_in[6];
    const float* wd = (const float*)d_in[7];
    float* out = (float*)d_out;

    char* p = (char*)d_ws;
    unsigned short* xb  = (unsigned short*)p; p += (size_t)N_TOK * D_DIM * 2;
    unsigned short* wgt = (unsigned short*)p; p += (size_t)NESH * D_DIM * F_DIM * 2;
    unsigned short* wut = (unsigned short*)p; p += (size_t)NESH * D_DIM * F_DIM * 2;
    unsigned short* wdt = (unsigned short*)p; p += (size_t)NESH * D_DIM * F_DIM * 2;
    unsigned short* h   = (unsigned short*)p; p += (size_t)MAX_ROWS * F_DIM * 2;
    int*   row_token  = (int*)p;   p += (size_t)MAX_ROWS * 4;
    int*   row_expert = (int*)p;   p += (size_t)MAX_ROWS * 4;
    float* row_weight = (float*)p; p += (size_t)MAX_ROWS * 4;
    int*   tk_i = (int*)p;         p += (size_t)N_TOK * 2 * 4;
    float* tk_w = (float*)p;       p += (size_t)N_TOK * 2 * 4;
    int*   meta = (int*)p;         p += 1024;
    if ((size_t)(p - (char*)d_ws) > ws_size) return;

    hipMemsetAsync(out, 0, (size_t)N_TOK * D_DIM * 4, stream);
    hipMemsetAsync(meta, 0, 256, stream);

    k_convert_x<<<N_TOK * D_DIM / 8 / 256, 256, 0, stream>>>(x, xb);
    k_transpose<<<27 * 256, 256, 0, stream>>>(wg, wu, wd, sg, su, sd, wgt, wut, wdt);
    k_router<<<N_TOK / 4, 256, 0, stream>>>(x, rw, tk_i, tk_w, meta);
    k_offsets<<<1, 64, 0, stream>>>(meta);
    k_prefill<<<MAX_ROWS / 256, 256, 0, stream>>>(row_token, row_expert, row_weight);
    k_scatter<<<N_TOK / 256, 256, 0, stream>>>(tk_i, tk_w, meta, row_token, row_expert, row_weight);
    k_gemm1<<<(MAX_ROWS / BM) * 8, 256, 0, stream>>>(xb, wgt, wut, row_token, row_expert, meta, h);
    k_gemm2<<<(MAX_ROWS / BM) * 8, 256, 0, stream>>>(h, wdt, row_token, row_weight, row_expert, meta, out);
}

// Round 3
// 645.050 us; speedup vs baseline: 1.1592x; 1.0785x over previous
//
#include <hip/hip_runtime.h>

#define N_TOK    8192
#define D_DIM    1024
#define F_DIM    1024
#define NESH     9          // 8 routed experts + shared as expert 8
#define MAX_ROWS 26624      // worst-case routed padded to 256 (18432) + shared (8192)
#define BM 256
#define BN 128
#define BK 64

// meta layout (ints)
#define MC 0    // cnt[8]
#define MF 8    // fill[8]
#define MO 16   // off_e[9]
#define MT 25   // total rows

typedef float  f4    __attribute__((ext_vector_type(4)));
typedef float  f32x4 __attribute__((ext_vector_type(4)));
typedef short  s16x8 __attribute__((ext_vector_type(8)));
typedef unsigned short u16x8 __attribute__((ext_vector_type(8)));

static __device__ __forceinline__ unsigned short f2bf(float f) {
    union { float f; unsigned u; } v; v.f = f;
    unsigned r = v.u + 0x7FFFu + ((v.u >> 16) & 1u);
    return (unsigned short)(r >> 16);
}

#define GLDS(gp, lp) __builtin_amdgcn_global_load_lds( \
    (const __attribute__((address_space(1))) void*)(gp), \
    (__attribute__((address_space(3))) void*)(lp), 16, 0, 0)

// LDS XOR swizzle (T2): byte ^= ((row&7)<<4)  -> bf16-index ^= ((row&7)<<3)
#define RSWZ(row, idx) ((idx) ^ (((row) & 7) << 3))

// ---------------------------------------------------------------- convert x
__global__ __launch_bounds__(256) void k_convert_x(
    const float* __restrict__ x, unsigned short* __restrict__ xb)
{
    int g = blockIdx.x * 256 + threadIdx.x;       // N*D/8 groups
    const f4* xs = (const f4*)x;
    f4 a = xs[2*g], b = xs[2*g+1];
    u16x8 o;
    o[0]=f2bf(a[0]); o[1]=f2bf(a[1]); o[2]=f2bf(a[2]); o[3]=f2bf(a[3]);
    o[4]=f2bf(b[0]); o[5]=f2bf(b[1]); o[6]=f2bf(b[2]); o[7]=f2bf(b[3]);
    *(u16x8*)&xb[8*(size_t)g] = o;
}

// ------------------------------------------- transpose+convert 27 matrices
__global__ __launch_bounds__(256) void k_transpose(
    const float* __restrict__ wg, const float* __restrict__ wu,
    const float* __restrict__ wd, const float* __restrict__ sg,
    const float* __restrict__ su, const float* __restrict__ sd,
    unsigned short* __restrict__ wgt, unsigned short* __restrict__ wut,
    unsigned short* __restrict__ wdt)
{
    int bx = blockIdx.x;
    int m = bx >> 8;                // 0..26
    int tile = bx & 255;
    int ty = tile >> 4, tx = tile & 15;
    int set = m / 9, e = m % 9;
    const float* src; unsigned short* dst;
    if (set == 0)      { src = (e < 8) ? wg + (size_t)e*1048576 : sg; dst = wgt + (size_t)e*1048576; }
    else if (set == 1) { src = (e < 8) ? wu + (size_t)e*1048576 : su; dst = wut + (size_t)e*1048576; }
    else               { src = (e < 8) ? wd + (size_t)e*1048576 : sd; dst = wdt + (size_t)e*1048576; }

    __shared__ __align__(16) unsigned short ts[64 * 80];
    int t = threadIdx.x;
    int rT0 = ty * 64, cT0 = tx * 64;
    #pragma unroll
    for (int i = 0; i < 16; i++) {
        int lin = t + i * 256;
        int mr = lin >> 6, mc = lin & 63;
        float v = src[(size_t)(cT0 + mr) * 1024 + rT0 + mc];
        ts[mc * 80 + mr] = f2bf(v);
    }
    __syncthreads();
    #pragma unroll
    for (int i = 0; i < 2; i++) {
        int r = (t >> 3) + i * 32;
        int c0 = (t & 7) * 8;
        *(u16x8*)&dst[(size_t)(rT0 + r) * 1024 + cT0 + c0] = *(u16x8*)&ts[r * 80 + c0];
    }
}

// ---------------------------------------------------------------- router
__global__ __launch_bounds__(256) void k_router(
    const float* __restrict__ x, const float* __restrict__ rw,
    int* __restrict__ tk_i, float* __restrict__ tk_w, int* __restrict__ meta)
{
    int wid = threadIdx.x >> 6, lane = threadIdx.x & 63;
    int n = blockIdx.x * 4 + wid;
    const float* xr = x + (size_t)n * D_DIM;
    float acc[8] = {0,0,0,0,0,0,0,0};
    #pragma unroll
    for (int it = 0; it < 16; it++) {
        int d = it * 64 + lane;
        float xv = xr[d];
        f4 r0 = *(const f4*)(rw + (size_t)d * 8);
        f4 r1 = *(const f4*)(rw + (size_t)d * 8 + 4);
        acc[0] += xv * r0[0]; acc[1] += xv * r0[1]; acc[2] += xv * r0[2]; acc[3] += xv * r0[3];
        acc[4] += xv * r1[0]; acc[5] += xv * r1[1]; acc[6] += xv * r1[2]; acc[7] += xv * r1[3];
    }
    #pragma unroll
    for (int e = 0; e < 8; e++)
        for (int off = 32; off; off >>= 1)
            acc[e] += __shfl_xor(acc[e], off, 64);
    if (lane == 0) {
        float mx = acc[0];
        for (int e = 1; e < 8; e++) mx = fmaxf(mx, acc[e]);
        float p[8], s = 0.f;
        for (int e = 0; e < 8; e++) { p[e] = expf(acc[e] - mx); s += p[e]; }
        int i0 = 0;
        for (int e = 1; e < 8; e++) if (p[e] > p[i0]) i0 = e;
        int i1 = (i0 == 0) ? 1 : 0;
        for (int e = 0; e < 8; e++) if (e != i0 && p[e] > p[i1]) i1 = e;
        float p0 = p[i0] / s, p1 = p[i1] / s;
        float rs = p0 + p1 + 1e-9f;
        tk_i[2*n] = i0;  tk_i[2*n+1] = i1;
        tk_w[2*n] = p0 / rs;  tk_w[2*n+1] = p1 / rs;
        atomicAdd(&meta[MC + i0], 1);
        atomicAdd(&meta[MC + i1], 1);
    }
}

__global__ void k_offsets(int* __restrict__ meta)
{
    if (threadIdx.x == 0) {
        int acc = 0;
        for (int e = 0; e < 8; e++) {
            meta[MO + e] = acc;
            acc += ((meta[MC + e] + 255) >> 8) << 8;   // pad to BM=256
        }
        meta[MO + 8] = acc;          // shared region start (mult of 256)
        meta[MT] = acc + N_TOK;      // total rows
    }
}

__global__ __launch_bounds__(256) void k_prefill(
    int* __restrict__ row_token, int* __restrict__ row_expert, float* __restrict__ row_weight)
{
    int i = blockIdx.x * 256 + threadIdx.x;
    row_token[i] = -1; row_expert[i] = 0; row_weight[i] = 0.f;
}

__global__ __launch_bounds__(256) void k_scatter(
    const int* __restrict__ tk_i, const float* __restrict__ tk_w, int* __restrict__ meta,
    int* __restrict__ row_token, int* __restrict__ row_expert, float* __restrict__ row_weight)
{
    int n = blockIdx.x * 256 + threadIdx.x;
    #pragma unroll
    for (int k = 0; k < 2; k++) {
        int e = tk_i[2*n + k];
        float w = tk_w[2*n + k];
        int pos = meta[MO + e] + atomicAdd(&meta[MF + e], 1);
        row_token[pos] = n; row_expert[pos] = e; row_weight[pos] = w;
    }
    int pos = meta[MO + 8] + n;
    row_token[pos] = n; row_expert[pos] = 8; row_weight[pos] = 1.f;
}

// ----------------------------------------------- GEMM1: gate+up, silu*mul -> h
// 512 threads, BM=256 x BN=128, double-buffered LDS (128KB), counted vmcnt.
__global__ __launch_bounds__(512, 2) void k_gemm1(
    const unsigned short* __restrict__ xb,
    const unsigned short* __restrict__ wgt,
    const unsigned short* __restrict__ wut,
    const int* __restrict__ row_token,
    const int* __restrict__ row_expert,
    const int* __restrict__ meta,
    unsigned short* __restrict__ h)
{
    const int total = meta[MT];
    const int rt = blockIdx.x >> 3, ct = blockIdx.x & 7;
    const int row0 = rt * BM;
    if (row0 >= total) return;
    const int e = row_expert[row0];

    __shared__ __align__(16) unsigned short sA[2 * BM * BK];   // 64KB
    __shared__ __align__(16) unsigned short sBg[2 * BN * BK];  // 32KB
    __shared__ __align__(16) unsigned short sBu[2 * BN * BK];  // 32KB

    const int t = threadIdx.x;            // 0..511
    const int lane = t & 63;
    const int wid = t >> 6;               // 0..7
    const int wr = wid >> 1, wc = wid & 1;

    // staging sources (pre-swizzled global chunk; LDS dest linear — rule #21)
    const unsigned short* asrc[4];
    #pragma unroll
    for (int i = 0; i < 4; i++) {
        int slot = t + i * 512;           // 0..2047
        int row = slot >> 3;              // 0..255
        int cg  = (slot & 7) ^ (row & 7);
        int tok = row_token[row0 + row];
        if (tok < 0) tok = 0;
        asrc[i] = xb + (size_t)tok * D_DIM + cg * 8;
    }
    const unsigned short* bsrcg[2];
    const unsigned short* bsrcu[2];
    #pragma unroll
    for (int i = 0; i < 2; i++) {
        int slot = t + i * 512;           // 0..1023
        int row = slot >> 3;              // 0..127
        int cg  = (slot & 7) ^ (row & 7);
        size_t off = ((size_t)e * F_DIM + ct * BN + row) * D_DIM + cg * 8;
        bsrcg[i] = wgt + off;
        bsrcu[i] = wut + off;
    }

    f32x4 accg[4][4] = {}, accu[4][4] = {};

#define STAGE1(bb, k0) do { \
    unsigned short* dA  = &sA[(bb) * (BM * BK)]; \
    unsigned short* dBg = &sBg[(bb) * (BN * BK)]; \
    unsigned short* dBu = &sBu[(bb) * (BN * BK)]; \
    _Pragma("unroll") \
    for (int i_ = 0; i_ < 4; i_++) GLDS(asrc[i_] + (k0), &dA[(t + i_ * 512) * 8]); \
    _Pragma("unroll") \
    for (int i_ = 0; i_ < 2; i_++) { \
        GLDS(bsrcg[i_] + (k0), &dBg[(t + i_ * 512) * 8]); \
        GLDS(bsrcu[i_] + (k0), &dBu[(t + i_ * 512) * 8]); \
    } } while (0)

#define COMPUTE1(bb) do { \
    const unsigned short* pA  = &sA[(bb) * (BM * BK)]; \
    const unsigned short* pBg = &sBg[(bb) * (BN * BK)]; \
    const unsigned short* pBu = &sBu[(bb) * (BN * BK)]; \
    _Pragma("unroll") \
    for (int kk = 0; kk < BK; kk += 32) { \
        const int koff = kk + (lane >> 4) * 8; \
        s16x8 a_[4], bg_[4], bu_[4]; \
        _Pragma("unroll") \
        for (int m_ = 0; m_ < 4; m_++) { \
            int row = wr * 64 + m_ * 16 + (lane & 15); \
            a_[m_] = *(const s16x8*)&pA[RSWZ(row, row * BK + koff)]; } \
        _Pragma("unroll") \
        for (int n_ = 0; n_ < 4; n_++) { \
            int row = wc * 64 + n_ * 16 + (lane & 15); \
            bg_[n_] = *(const s16x8*)&pBg[RSWZ(row, row * BK + koff)]; \
            bu_[n_] = *(const s16x8*)&pBu[RSWZ(row, row * BK + koff)]; } \
        _Pragma("unroll") \
        for (int m_ = 0; m_ < 4; m_++) \
            _Pragma("unroll") \
            for (int n_ = 0; n_ < 4; n_++) { \
                accg[m_][n_] = __builtin_amdgcn_mfma_f32_16x16x32_bf16(a_[m_], bg_[n_], accg[m_][n_], 0, 0, 0); \
                accu[m_][n_] = __builtin_amdgcn_mfma_f32_16x16x32_bf16(a_[m_], bu_[n_], accu[m_][n_], 0, 0, 0); } \
    } } while (0)

    STAGE1(0, 0);
    int cur = 0;
    for (int k0 = 0; k0 < D_DIM - BK; k0 += BK) {
        STAGE1(cur ^ 1, k0 + BK);
        asm volatile("s_waitcnt vmcnt(8)" ::: "memory");  // cur tile landed; next 8 in flight
        __builtin_amdgcn_s_barrier();
        __builtin_amdgcn_s_setprio(1);
        COMPUTE1(cur);
        __builtin_amdgcn_s_setprio(0);
        asm volatile("" ::: "memory");
        __builtin_amdgcn_s_barrier();
        cur ^= 1;
    }
    asm volatile("s_waitcnt vmcnt(0)" ::: "memory");
    __builtin_amdgcn_s_barrier();
    __builtin_amdgcn_s_setprio(1);
    COMPUTE1(cur);
    __builtin_amdgcn_s_setprio(0);

    #pragma unroll
    for (int m = 0; m < 4; m++)
        #pragma unroll
        for (int r = 0; r < 4; r++) {
            int grow = row0 + wr * 64 + m * 16 + (lane >> 4) * 4 + r;
            unsigned short* hrow = h + (size_t)grow * F_DIM + ct * BN + wc * 64 + (lane & 15);
            #pragma unroll
            for (int n = 0; n < 4; n++) {
                float g = accg[m][n][r], u = accu[m][n][r];
                float sv = g / (1.f + __expf(-g));
                hrow[n * 16] = f2bf(sv * u);
            }
        }
#undef STAGE1
#undef COMPUTE1
}

// ----------------------------------------------- GEMM2: down + weighted add
__global__ __launch_bounds__(512, 2) void k_gemm2(
    const unsigned short* __restrict__ h,
    const unsigned short* __restrict__ wdt,
    const int* __restrict__ row_token,
    const float* __restrict__ row_weight,
    const int* __restrict__ row_expert,
    const int* __restrict__ meta,
    float* __restrict__ out)
{
    const int total = meta[MT];
    const int rt = blockIdx.x >> 3, ct = blockIdx.x & 7;
    const int row0 = rt * BM;
    if (row0 >= total) return;
    const int e = row_expert[row0];

    __shared__ __align__(16) unsigned short sA[2 * BM * BK];   // 64KB
    __shared__ __align__(16) unsigned short sB[2 * BN * BK];   // 32KB

    const int t = threadIdx.x;
    const int lane = t & 63;
    const int wid = t >> 6;
    const int wr = wid >> 1, wc = wid & 1;

    const unsigned short* asrc[4];
    #pragma unroll
    for (int i = 0; i < 4; i++) {
        int slot = t + i * 512;
        int row = slot >> 3;
        int cg  = (slot & 7) ^ (row & 7);
        asrc[i] = h + (size_t)(row0 + row) * F_DIM + cg * 8;
    }
    const unsigned short* bsrc[2];
    #pragma unroll
    for (int i = 0; i < 2; i++) {
        int slot = t + i * 512;
        int row = slot >> 3;
        int cg  = (slot & 7) ^ (row & 7);
        bsrc[i] = wdt + ((size_t)e * D_DIM + ct * BN + row) * F_DIM + cg * 8;
    }

    f32x4 acc[4][4] = {};

#define STAGE2(bb, k0) do { \
    unsigned short* dA = &sA[(bb) * (BM * BK)]; \
    unsigned short* dB = &sB[(bb) * (BN * BK)]; \
    _Pragma("unroll") \
    for (int i_ = 0; i_ < 4; i_++) GLDS(asrc[i_] + (k0), &dA[(t + i_ * 512) * 8]); \
    _Pragma("unroll") \
    for (int i_ = 0; i_ < 2; i_++) GLDS(bsrc[i_] + (k0), &dB[(t + i_ * 512) * 8]); \
    } while (0)

#define COMPUTE2(bb) do { \
    const unsigned short* pA = &sA[(bb) * (BM * BK)]; \
    const unsigned short* pB = &sB[(bb) * (BN * BK)]; \
    _Pragma("unroll") \
    for (int kk = 0; kk < BK; kk += 32) { \
        const int koff = kk + (lane >> 4) * 8; \
        s16x8 a_[4], b_[4]; \
        _Pragma("unroll") \
        for (int m_ = 0; m_ < 4; m_++) { \
            int row = wr * 64 + m_ * 16 + (lane & 15); \
            a_[m_] = *(const s16x8*)&pA[RSWZ(row, row * BK + koff)]; } \
        _Pragma("unroll") \
        for (int n_ = 0; n_ < 4; n_++) { \
            int row = wc * 64 + n_ * 16 + (lane & 15); \
            b_[n_] = *(const s16x8*)&pB[RSWZ(row, row * BK + koff)]; } \
        _Pragma("unroll") \
        for (int m_ = 0; m_ < 4; m_++) \
            _Pragma("unroll") \
            for (int n_ = 0; n_ < 4; n_++) \
                acc[m_][n_] = __builtin_amdgcn_mfma_f32_16x16x32_bf16(a_[m_], b_[n_], acc[m_][n_], 0, 0, 0); \
    } } while (0)

    STAGE2(0, 0);
    int cur = 0;
    for (int k0 = 0; k0 < F_DIM - BK; k0 += BK) {
        STAGE2(cur ^ 1, k0 + BK);
        asm volatile("s_waitcnt vmcnt(6)" ::: "memory");
        __builtin_amdgcn_s_barrier();
        __builtin_amdgcn_s_setprio(1);
        COMPUTE2(cur);
        __builtin_amdgcn_s_setprio(0);
        asm volatile("" ::: "memory");
        __builtin_amdgcn_s_barrier();
        cur ^= 1;
    }
    asm volatile("s_waitcnt vmcnt(0)" ::: "memory");
    __builtin_amdgcn_s_barrier();
    __builtin_amdgcn_s_setprio(1);
    COMPUTE2(cur);
    __builtin_amdgcn_s_setprio(0);

    #pragma unroll
    for (int m = 0; m < 4; m++)
        #pragma unroll
        for (int r = 0; r < 4; r++) {
            int grow = row0 + wr * 64 + m * 16 + (lane >> 4) * 4 + r;
            int tok = row_token[grow];
            if (tok < 0) continue;
            float w = row_weight[grow];
            float* orow = out + (size_t)tok * D_DIM + ct * BN + wc * 64 + (lane & 15);
            #pragma unroll
            for (int n = 0; n < 4; n++)
                atomicAdd(&orow[n * 16], w * acc[m][n][r]);
        }
#undef STAGE2
#undef COMPUTE2
}

// ---------------------------------------------------------------- launch
extern "C" void kernel_launch(void* const* d_in, const int* in_sizes, int n_in,
                              void* d_out, int out_size, void* d_ws, size_t ws_size,
                              hipStream_t stream)
{
    const float* x  = (const float*)d_in[0];
    const float* rw = (const float*)d_in[1];
    const float* sg = (const float*)d_in[2];
    const float* su = (const float*)d_in[3];
    const float* sd = (const float*)d_in[4];
    const float* wg = (const float*)d_in[5];
    const float* wu = (const float*)d_in[6];
    const float* wd = (const float*)d_in[7];
    float* out = (float*)d_out;

    char* p = (char*)d_ws;
    unsigned short* xb  = (unsigned short*)p; p += (size_t)N_TOK * D_DIM * 2;
    unsigned short* wgt = (unsigned short*)p; p += (size_t)NESH * D_DIM * F_DIM * 2;
    unsigned short* wut = (unsigned short*)p; p += (size_t)NESH * D_DIM * F_DIM * 2;
    unsigned short* wdt = (unsigned short*)p; p += (size_t)NESH * D_DIM * F_DIM * 2;
    unsigned short* h   = (unsigned short*)p; p += (size_t)MAX_ROWS * F_DIM * 2;
    int*   row_token  = (int*)p;   p += (size_t)MAX_ROWS * 4;
    int*   row_expert = (int*)p;   p += (size_t)MAX_ROWS * 4;
    float* row_weight = (float*)p; p += (size_t)MAX_ROWS * 4;
    int*   tk_i = (int*)p;         p += (size_t)N_TOK * 2 * 4;
    float* tk_w = (float*)p;       p += (size_t)N_TOK * 2 * 4;
    int*   meta = (int*)p;         p += 1024;
    if ((size_t)(p - (char*)d_ws) > ws_size) return;

    hipMemsetAsync(out, 0, (size_t)N_TOK * D_DIM * 4, stream);
    hipMemsetAsync(meta, 0, 256, stream);

    k_convert_x<<<N_TOK * D_DIM / 8 / 256, 256, 0, stream>>>(x, xb);
    k_transpose<<<27 * 256, 256, 0, stream>>>(wg, wu, wd, sg, su, sd, wgt, wut, wdt);
    k_router<<<N_TOK / 4, 256, 0, stream>>>(x, rw, tk_i, tk_w, meta);
    k_offsets<<<1, 64, 0, stream>>>(meta);
    k_prefill<<<MAX_ROWS / 256, 256, 0, stream>>>(row_token, row_expert, row_weight);
    k_scatter<<<N_TOK / 256, 256, 0, stream>>>(tk_i, tk_w, meta, row_token, row_expert, row_weight);
    k_gemm1<<<(MAX_ROWS / BM) * 8, 512, 0, stream>>>(xb, wgt, wut, row_token, row_expert, meta, h);
    k_gemm2<<<(MAX_ROWS / BM) * 8, 512, 0, stream>>>(h, wdt, row_token, row_weight, row_expert, meta, out);
}

// Round 4
// 400.571 us; speedup vs baseline: 1.8668x; 1.6103x over previous
//
#include <hip/hip_runtime.h>

#define N_TOK    8192
#define D_DIM    1024
#define F_DIM    1024
#define NESH     9          // 8 routed experts + shared as expert 8
#define MAX_ROWS 26624      // worst-case routed padded to 256 (18432) + shared (8192)
#define BM 256
#define BN 128
#define BK 64

// meta layout (ints)
#define MO 16   // off_e[9]
#define MT 25   // total rows

typedef float  f4    __attribute__((ext_vector_type(4)));
typedef float  f32x4 __attribute__((ext_vector_type(4)));
typedef short  s16x8 __attribute__((ext_vector_type(8)));
typedef unsigned short u16x8 __attribute__((ext_vector_type(8)));

static __device__ __forceinline__ unsigned short f2bf(float f) {
    union { float f; unsigned u; } v; v.f = f;
    unsigned r = v.u + 0x7FFFu + ((v.u >> 16) & 1u);
    return (unsigned short)(r >> 16);
}

#define GLDS(gp, lp) __builtin_amdgcn_global_load_lds( \
    (const __attribute__((address_space(1))) void*)(gp), \
    (__attribute__((address_space(3))) void*)(lp), 16, 0, 0)

// LDS XOR swizzle (T2): byte ^= ((row&7)<<4)  -> bf16-index ^= ((row&7)<<3)
#define RSWZ(row, idx) ((idx) ^ (((row) & 7) << 3))

// ---------------------------------------------------------------- convert x
__global__ __launch_bounds__(256) void k_convert_x(
    const float* __restrict__ x, unsigned short* __restrict__ xb)
{
    int g = blockIdx.x * 256 + threadIdx.x;       // N*D/8 groups
    const f4* xs = (const f4*)x;
    f4 a = xs[2*g], b = xs[2*g+1];
    u16x8 o;
    o[0]=f2bf(a[0]); o[1]=f2bf(a[1]); o[2]=f2bf(a[2]); o[3]=f2bf(a[3]);
    o[4]=f2bf(b[0]); o[5]=f2bf(b[1]); o[6]=f2bf(b[2]); o[7]=f2bf(b[3]);
    *(u16x8*)&xb[8*(size_t)g] = o;
}

// ------------------------------------------- transpose+convert 27 matrices
__global__ __launch_bounds__(256) void k_transpose(
    const float* __restrict__ wg, const float* __restrict__ wu,
    const float* __restrict__ wd, const float* __restrict__ sg,
    const float* __restrict__ su, const float* __restrict__ sd,
    unsigned short* __restrict__ wgt, unsigned short* __restrict__ wut,
    unsigned short* __restrict__ wdt)
{
    int bx = blockIdx.x;
    int m = bx >> 8;                // 0..26
    int tile = bx & 255;
    int ty = tile >> 4, tx = tile & 15;
    int set = m / 9, e = m % 9;
    const float* src; unsigned short* dst;
    if (set == 0)      { src = (e < 8) ? wg + (size_t)e*1048576 : sg; dst = wgt + (size_t)e*1048576; }
    else if (set == 1) { src = (e < 8) ? wu + (size_t)e*1048576 : su; dst = wut + (size_t)e*1048576; }
    else               { src = (e < 8) ? wd + (size_t)e*1048576 : sd; dst = wdt + (size_t)e*1048576; }

    __shared__ __align__(16) unsigned short ts[64 * 80];
    int t = threadIdx.x;
    int rT0 = ty * 64, cT0 = tx * 64;
    #pragma unroll
    for (int i = 0; i < 16; i++) {
        int lin = t + i * 256;
        int mr = lin >> 6, mc = lin & 63;
        float v = src[(size_t)(cT0 + mr) * 1024 + rT0 + mc];
        ts[mc * 80 + mr] = f2bf(v);
    }
    __syncthreads();
    #pragma unroll
    for (int i = 0; i < 2; i++) {
        int r = (t >> 3) + i * 32;
        int c0 = (t & 7) * 8;
        *(u16x8*)&dst[(size_t)(rT0 + r) * 1024 + cT0 + c0] = *(u16x8*)&ts[r * 80 + c0];
    }
}

// ---------------------------------------------------------------- router
// logits + top2 only; NO global atomics (the 16384-atomics-on-one-line storm
// was 195us — Guideline 12).
__global__ __launch_bounds__(256) void k_router(
    const float* __restrict__ x, const float* __restrict__ rw,
    int* __restrict__ tk_i, float* __restrict__ tk_w)
{
    int wid = threadIdx.x >> 6, lane = threadIdx.x & 63;
    int n = blockIdx.x * 4 + wid;
    const float* xr = x + (size_t)n * D_DIM;
    float acc[8] = {0,0,0,0,0,0,0,0};
    #pragma unroll
    for (int it = 0; it < 16; it++) {
        int d = it * 64 + lane;
        float xv = xr[d];
        f4 r0 = *(const f4*)(rw + (size_t)d * 8);
        f4 r1 = *(const f4*)(rw + (size_t)d * 8 + 4);
        acc[0] += xv * r0[0]; acc[1] += xv * r0[1]; acc[2] += xv * r0[2]; acc[3] += xv * r0[3];
        acc[4] += xv * r1[0]; acc[5] += xv * r1[1]; acc[6] += xv * r1[2]; acc[7] += xv * r1[3];
    }
    #pragma unroll
    for (int e = 0; e < 8; e++)
        for (int off = 32; off; off >>= 1)
            acc[e] += __shfl_xor(acc[e], off, 64);
    if (lane == 0) {
        float mx = acc[0];
        for (int e = 1; e < 8; e++) mx = fmaxf(mx, acc[e]);
        float p[8], s = 0.f;
        for (int e = 0; e < 8; e++) { p[e] = expf(acc[e] - mx); s += p[e]; }
        int i0 = 0;
        for (int e = 1; e < 8; e++) if (p[e] > p[i0]) i0 = e;
        int i1 = (i0 == 0) ? 1 : 0;
        for (int e = 0; e < 8; e++) if (e != i0 && p[e] > p[i1]) i1 = e;
        float p0 = p[i0] / s, p1 = p[i1] / s;
        float rs = p0 + p1 + 1e-9f;
        tk_i[2*n] = i0;  tk_i[2*n+1] = i1;
        tk_w[2*n] = p0 / rs;  tk_w[2*n+1] = p1 / rs;
    }
}

__global__ __launch_bounds__(256) void k_prefill(
    int* __restrict__ row_token, int* __restrict__ row_expert, float* __restrict__ row_weight)
{
    int i = blockIdx.x * 256 + threadIdx.x;
    row_token[i] = -1; row_expert[i] = 0; row_weight[i] = 0.f;
}

// --------------------------------- count + offsets + scatter, ONE block, 0 atomics
__global__ __launch_bounds__(1024) void k_count_scatter(
    const int* __restrict__ tk_i, const float* __restrict__ tk_w,
    int* __restrict__ meta,
    int* __restrict__ row_token, int* __restrict__ row_expert, float* __restrict__ row_weight)
{
    __shared__ int cnt[1024 * 9];   // [thread][expert], stride 9 to spread banks
    __shared__ int tot[8];
    __shared__ int off[9];
    const int t = threadIdx.x;
    const int lane = t & 63;
    const int wid = t >> 6;         // 0..15

    #pragma unroll
    for (int e = 0; e < 8; e++) cnt[t * 9 + e] = 0;
    __syncthreads();

    // phase 1: per-thread histogram of its 8 tokens (16 entries)
    #pragma unroll
    for (int j = 0; j < 8; j++) {
        int n = t * 8 + j;
        cnt[t * 9 + tk_i[2 * n]]++;
        cnt[t * 9 + tk_i[2 * n + 1]]++;
    }
    __syncthreads();

    // phase 2: wave e (e<8) computes exclusive prefix over 1024 threads for expert e
    if (wid < 8) {
        const int e = wid;
        int carry = 0;
        for (int c = 0; c < 16; c++) {
            int i = c * 64 + lane;
            int v = cnt[i * 9 + e];
            int s = v;
            #pragma unroll
            for (int d = 1; d < 64; d <<= 1) {
                int u = __shfl_up(s, d, 64);
                if (lane >= d) s += u;
            }
            cnt[i * 9 + e] = s - v + carry;   // exclusive base for thread i
            carry += __shfl(s, 63, 64);
        }
        if (lane == 0) tot[e] = carry;
    }
    __syncthreads();

    if (t == 0) {
        int acc = 0;
        #pragma unroll
        for (int e = 0; e < 8; e++) {
            off[e] = acc;
            meta[MO + e] = acc;
            acc += ((tot[e] + 255) >> 8) << 8;   // pad to BM=256
        }
        off[8] = acc;
        meta[MO + 8] = acc;
        meta[MT] = acc + N_TOK;
    }
    __syncthreads();

    // phase 3: deterministic scatter (cnt[t][e] now = running position base)
    #pragma unroll
    for (int j = 0; j < 8; j++) {
        int n = t * 8 + j;
        #pragma unroll
        for (int k = 0; k < 2; k++) {
            int e = tk_i[2 * n + k];
            float w = tk_w[2 * n + k];
            int pos = off[e] + cnt[t * 9 + e];
            cnt[t * 9 + e] = cnt[t * 9 + e] + 1;
            row_token[pos] = n; row_expert[pos] = e; row_weight[pos] = w;
        }
        int ps = off[8] + n;
        row_token[ps] = n; row_expert[ps] = 8; row_weight[ps] = 1.f;
    }
}

// ----------------------------------------------- GEMM1: gate+up, silu*mul -> h
// 512 threads, BM=256 x BN=128, double-buffered LDS (128KB), counted vmcnt.
__global__ __launch_bounds__(512, 2) void k_gemm1(
    const unsigned short* __restrict__ xb,
    const unsigned short* __restrict__ wgt,
    const unsigned short* __restrict__ wut,
    const int* __restrict__ row_token,
    const int* __restrict__ row_expert,
    const int* __restrict__ meta,
    unsigned short* __restrict__ h)
{
    const int total = meta[MT];
    const int rt = blockIdx.x >> 3, ct = blockIdx.x & 7;
    const int row0 = rt * BM;
    if (row0 >= total) return;
    const int e = row_expert[row0];

    __shared__ __align__(16) unsigned short sA[2 * BM * BK];   // 64KB
    __shared__ __align__(16) unsigned short sBg[2 * BN * BK];  // 32KB
    __shared__ __align__(16) unsigned short sBu[2 * BN * BK];  // 32KB

    const int t = threadIdx.x;            // 0..511
    const int lane = t & 63;
    const int wid = t >> 6;               // 0..7
    const int wr = wid >> 1, wc = wid & 1;

    // staging sources (pre-swizzled global chunk; LDS dest linear — rule #21)
    const unsigned short* asrc[4];
    #pragma unroll
    for (int i = 0; i < 4; i++) {
        int slot = t + i * 512;           // 0..2047
        int row = slot >> 3;              // 0..255
        int cg  = (slot & 7) ^ (row & 7);
        int tok = row_token[row0 + row];
        if (tok < 0) tok = 0;
        asrc[i] = xb + (size_t)tok * D_DIM + cg * 8;
    }
    const unsigned short* bsrcg[2];
    const unsigned short* bsrcu[2];
    #pragma unroll
    for (int i = 0; i < 2; i++) {
        int slot = t + i * 512;           // 0..1023
        int row = slot >> 3;              // 0..127
        int cg  = (slot & 7) ^ (row & 7);
        size_t off = ((size_t)e * F_DIM + ct * BN + row) * D_DIM + cg * 8;
        bsrcg[i] = wgt + off;
        bsrcu[i] = wut + off;
    }

    f32x4 accg[4][4] = {}, accu[4][4] = {};

#define STAGE1(bb, k0) do { \
    unsigned short* dA  = &sA[(bb) * (BM * BK)]; \
    unsigned short* dBg = &sBg[(bb) * (BN * BK)]; \
    unsigned short* dBu = &sBu[(bb) * (BN * BK)]; \
    _Pragma("unroll") \
    for (int i_ = 0; i_ < 4; i_++) GLDS(asrc[i_] + (k0), &dA[(t + i_ * 512) * 8]); \
    _Pragma("unroll") \
    for (int i_ = 0; i_ < 2; i_++) { \
        GLDS(bsrcg[i_] + (k0), &dBg[(t + i_ * 512) * 8]); \
        GLDS(bsrcu[i_] + (k0), &dBu[(t + i_ * 512) * 8]); \
    } } while (0)

#define COMPUTE1(bb) do { \
    const unsigned short* pA  = &sA[(bb) * (BM * BK)]; \
    const unsigned short* pBg = &sBg[(bb) * (BN * BK)]; \
    const unsigned short* pBu = &sBu[(bb) * (BN * BK)]; \
    _Pragma("unroll") \
    for (int kk = 0; kk < BK; kk += 32) { \
        const int koff = kk + (lane >> 4) * 8; \
        s16x8 a_[4], bg_[4], bu_[4]; \
        _Pragma("unroll") \
        for (int m_ = 0; m_ < 4; m_++) { \
            int row = wr * 64 + m_ * 16 + (lane & 15); \
            a_[m_] = *(const s16x8*)&pA[RSWZ(row, row * BK + koff)]; } \
        _Pragma("unroll") \
        for (int n_ = 0; n_ < 4; n_++) { \
            int row = wc * 64 + n_ * 16 + (lane & 15); \
            bg_[n_] = *(const s16x8*)&pBg[RSWZ(row, row * BK + koff)]; \
            bu_[n_] = *(const s16x8*)&pBu[RSWZ(row, row * BK + koff)]; } \
        _Pragma("unroll") \
        for (int m_ = 0; m_ < 4; m_++) \
            _Pragma("unroll") \
            for (int n_ = 0; n_ < 4; n_++) { \
                accg[m_][n_] = __builtin_amdgcn_mfma_f32_16x16x32_bf16(a_[m_], bg_[n_], accg[m_][n_], 0, 0, 0); \
                accu[m_][n_] = __builtin_amdgcn_mfma_f32_16x16x32_bf16(a_[m_], bu_[n_], accu[m_][n_], 0, 0, 0); } \
    } } while (0)

    STAGE1(0, 0);
    int cur = 0;
    for (int k0 = 0; k0 < D_DIM - BK; k0 += BK) {
        STAGE1(cur ^ 1, k0 + BK);
        asm volatile("s_waitcnt vmcnt(8)" ::: "memory");  // cur tile landed; next 8 in flight
        __builtin_amdgcn_s_barrier();
        __builtin_amdgcn_s_setprio(1);
        COMPUTE1(cur);
        __builtin_amdgcn_s_setprio(0);
        asm volatile("" ::: "memory");
        __builtin_amdgcn_s_barrier();
        cur ^= 1;
    }
    asm volatile("s_waitcnt vmcnt(0)" ::: "memory");
    __builtin_amdgcn_s_barrier();
    __builtin_amdgcn_s_setprio(1);
    COMPUTE1(cur);
    __builtin_amdgcn_s_setprio(0);

    #pragma unroll
    for (int m = 0; m < 4; m++)
        #pragma unroll
        for (int r = 0; r < 4; r++) {
            int grow = row0 + wr * 64 + m * 16 + (lane >> 4) * 4 + r;
            unsigned short* hrow = h + (size_t)grow * F_DIM + ct * BN + wc * 64 + (lane & 15);
            #pragma unroll
            for (int n = 0; n < 4; n++) {
                float g = accg[m][n][r], u = accu[m][n][r];
                float sv = g / (1.f + __expf(-g));
                hrow[n * 16] = f2bf(sv * u);
            }
        }
#undef STAGE1
#undef COMPUTE1
}

// ----------------------------------------------- GEMM2: down + weighted add
__global__ __launch_bounds__(512, 2) void k_gemm2(
    const unsigned short* __restrict__ h,
    const unsigned short* __restrict__ wdt,
    const int* __restrict__ row_token,
    const float* __restrict__ row_weight,
    const int* __restrict__ row_expert,
    const int* __restrict__ meta,
    float* __restrict__ out)
{
    const int total = meta[MT];
    const int rt = blockIdx.x >> 3, ct = blockIdx.x & 7;
    const int row0 = rt * BM;
    if (row0 >= total) return;
    const int e = row_expert[row0];

    __shared__ __align__(16) unsigned short sA[2 * BM * BK];   // 64KB
    __shared__ __align__(16) unsigned short sB[2 * BN * BK];   // 32KB

    const int t = threadIdx.x;
    const int lane = t & 63;
    const int wid = t >> 6;
    const int wr = wid >> 1, wc = wid & 1;

    const unsigned short* asrc[4];
    #pragma unroll
    for (int i = 0; i < 4; i++) {
        int slot = t + i * 512;
        int row = slot >> 3;
        int cg  = (slot & 7) ^ (row & 7);
        asrc[i] = h + (size_t)(row0 + row) * F_DIM + cg * 8;
    }
    const unsigned short* bsrc[2];
    #pragma unroll
    for (int i = 0; i < 2; i++) {
        int slot = t + i * 512;
        int row = slot >> 3;
        int cg  = (slot & 7) ^ (row & 7);
        bsrc[i] = wdt + ((size_t)e * D_DIM + ct * BN + row) * F_DIM + cg * 8;
    }

    f32x4 acc[4][4] = {};

#define STAGE2(bb, k0) do { \
    unsigned short* dA = &sA[(bb) * (BM * BK)]; \
    unsigned short* dB = &sB[(bb) * (BN * BK)]; \
    _Pragma("unroll") \
    for (int i_ = 0; i_ < 4; i_++) GLDS(asrc[i_] + (k0), &dA[(t + i_ * 512) * 8]); \
    _Pragma("unroll") \
    for (int i_ = 0; i_ < 2; i_++) GLDS(bsrc[i_] + (k0), &dB[(t + i_ * 512) * 8]); \
    } while (0)

#define COMPUTE2(bb) do { \
    const unsigned short* pA = &sA[(bb) * (BM * BK)]; \
    const unsigned short* pB = &sB[(bb) * (BN * BK)]; \
    _Pragma("unroll") \
    for (int kk = 0; kk < BK; kk += 32) { \
        const int koff = kk + (lane >> 4) * 8; \
        s16x8 a_[4], b_[4]; \
        _Pragma("unroll") \
        for (int m_ = 0; m_ < 4; m_++) { \
            int row = wr * 64 + m_ * 16 + (lane & 15); \
            a_[m_] = *(const s16x8*)&pA[RSWZ(row, row * BK + koff)]; } \
        _Pragma("unroll") \
        for (int n_ = 0; n_ < 4; n_++) { \
            int row = wc * 64 + n_ * 16 + (lane & 15); \
            b_[n_] = *(const s16x8*)&pB[RSWZ(row, row * BK + koff)]; } \
        _Pragma("unroll") \
        for (int m_ = 0; m_ < 4; m_++) \
            _Pragma("unroll") \
            for (int n_ = 0; n_ < 4; n_++) \
                acc[m_][n_] = __builtin_amdgcn_mfma_f32_16x16x32_bf16(a_[m_], b_[n_], acc[m_][n_], 0, 0, 0); \
    } } while (0)

    STAGE2(0, 0);
    int cur = 0;
    for (int k0 = 0; k0 < F_DIM - BK; k0 += BK) {
        STAGE2(cur ^ 1, k0 + BK);
        asm volatile("s_waitcnt vmcnt(6)" ::: "memory");
        __builtin_amdgcn_s_barrier();
        __builtin_amdgcn_s_setprio(1);
        COMPUTE2(cur);
        __builtin_amdgcn_s_setprio(0);
        asm volatile("" ::: "memory");
        __builtin_amdgcn_s_barrier();
        cur ^= 1;
    }
    asm volatile("s_waitcnt vmcnt(0)" ::: "memory");
    __builtin_amdgcn_s_barrier();
    __builtin_amdgcn_s_setprio(1);
    COMPUTE2(cur);
    __builtin_amdgcn_s_setprio(0);

    #pragma unroll
    for (int m = 0; m < 4; m++)
        #pragma unroll
        for (int r = 0; r < 4; r++) {
            int grow = row0 + wr * 64 + m * 16 + (lane >> 4) * 4 + r;
            int tok = row_token[grow];
            if (tok < 0) continue;
            float w = row_weight[grow];
            float* orow = out + (size_t)tok * D_DIM + ct * BN + wc * 64 + (lane & 15);
            #pragma unroll
            for (int n = 0; n < 4; n++)
                atomicAdd(&orow[n * 16], w * acc[m][n][r]);
        }
#undef STAGE2
#undef COMPUTE2
}

// ---------------------------------------------------------------- launch
extern "C" void kernel_launch(void* const* d_in, const int* in_sizes, int n_in,
                              void* d_out, int out_size, void* d_ws, size_t ws_size,
                              hipStream_t stream)
{
    const float* x  = (const float*)d_in[0];
    const float* rw = (const float*)d_in[1];
    const float* sg = (const float*)d_in[2];
    const float* su = (const float*)d_in[3];
    const float* sd = (const float*)d_in[4];
    const float* wg = (const float*)d_in[5];
    const float* wu = (const float*)d_in[6];
    const float* wd = (const float*)d_in[7];
    float* out = (float*)d_out;

    char* p = (char*)d_ws;
    unsigned short* xb  = (unsigned short*)p; p += (size_t)N_TOK * D_DIM * 2;
    unsigned short* wgt = (unsigned short*)p; p += (size_t)NESH * D_DIM * F_DIM * 2;
    unsigned short* wut = (unsigned short*)p; p += (size_t)NESH * D_DIM * F_DIM * 2;
    unsigned short* wdt = (unsigned short*)p; p += (size_t)NESH * D_DIM * F_DIM * 2;
    unsigned short* h   = (unsigned short*)p; p += (size_t)MAX_ROWS * F_DIM * 2;
    int*   row_token  = (int*)p;   p += (size_t)MAX_ROWS * 4;
    int*   row_expert = (int*)p;   p += (size_t)MAX_ROWS * 4;
    float* row_weight = (float*)p; p += (size_t)MAX_ROWS * 4;
    int*   tk_i = (int*)p;         p += (size_t)N_TOK * 2 * 4;
    float* tk_w = (float*)p;       p += (size_t)N_TOK * 2 * 4;
    int*   meta = (int*)p;         p += 1024;
    if ((size_t)(p - (char*)d_ws) > ws_size) return;

    hipMemsetAsync(out, 0, (size_t)N_TOK * D_DIM * 4, stream);

    k_convert_x<<<N_TOK * D_DIM / 8 / 256, 256, 0, stream>>>(x, xb);
    k_transpose<<<27 * 256, 256, 0, stream>>>(wg, wu, wd, sg, su, sd, wgt, wut, wdt);
    k_router<<<N_TOK / 4, 256, 0, stream>>>(x, rw, tk_i, tk_w);
    k_prefill<<<MAX_ROWS / 256, 256, 0, stream>>>(row_token, row_expert, row_weight);
    k_count_scatter<<<1, 1024, 0, stream>>>(tk_i, tk_w, meta, row_token, row_expert, row_weight);
    k_gemm1<<<(MAX_ROWS / BM) * 8, 512, 0, stream>>>(xb, wgt, wut, row_token, row_expert, meta, h);
    k_gemm2<<<(MAX_ROWS / BM) * 8, 512, 0, stream>>>(h, wdt, row_token, row_weight, row_expert, meta, out);
}

// Round 5
// 306.754 us; speedup vs baseline: 2.4377x; 1.3058x over previous
//
#include <hip/hip_runtime.h>

#define N_TOK    8192
#define D_DIM    1024
#define F_DIM    1024
#define NESH     9          // 8 routed experts + shared as expert 8
#define MAX_RTD  18432      // worst-case routed rows padded to 256 (16384 + 8*255 -> 18432)
#define MAX_ROWS 26624      // MAX_RTD + shared (8192)
#define BM 256
#define BN 128
#define BK 64
#define BN2 256             // gemm2 col tile

// meta layout (ints)
#define MO 16   // off_e[9]
#define MT 25   // total rows

typedef float  f4    __attribute__((ext_vector_type(4)));
typedef float  f32x4 __attribute__((ext_vector_type(4)));
typedef short  s16x8 __attribute__((ext_vector_type(8)));
typedef unsigned short u16x8 __attribute__((ext_vector_type(8)));

static __device__ __forceinline__ unsigned short f2bf(float f) {
    union { float f; unsigned u; } v; v.f = f;
    unsigned r = v.u + 0x7FFFu + ((v.u >> 16) & 1u);
    return (unsigned short)(r >> 16);
}
static __device__ __forceinline__ float bf2f(unsigned short u) {
    union { unsigned u; float f; } v; v.u = ((unsigned)u) << 16; return v.f;
}

#define GLDS(gp, lp) __builtin_amdgcn_global_load_lds( \
    (const __attribute__((address_space(1))) void*)(gp), \
    (__attribute__((address_space(3))) void*)(lp), 16, 0, 0)

// LDS XOR swizzle (T2): byte ^= ((row&7)<<4)  -> bf16-index ^= ((row&7)<<3)
#define RSWZ(row, idx) ((idx) ^ (((row) & 7) << 3))

// ---------------------------------------------------------------- convert x
__global__ __launch_bounds__(256) void k_convert_x(
    const float* __restrict__ x, unsigned short* __restrict__ xb)
{
    int g = blockIdx.x * 256 + threadIdx.x;       // N*D/8 groups
    const f4* xs = (const f4*)x;
    f4 a = xs[2*g], b = xs[2*g+1];
    u16x8 o;
    o[0]=f2bf(a[0]); o[1]=f2bf(a[1]); o[2]=f2bf(a[2]); o[3]=f2bf(a[3]);
    o[4]=f2bf(b[0]); o[5]=f2bf(b[1]); o[6]=f2bf(b[2]); o[7]=f2bf(b[3]);
    *(u16x8*)&xb[8*(size_t)g] = o;
}

// ------------------------------------------- transpose+convert 27 matrices
__global__ __launch_bounds__(256) void k_transpose(
    const float* __restrict__ wg, const float* __restrict__ wu,
    const float* __restrict__ wd, const float* __restrict__ sg,
    const float* __restrict__ su, const float* __restrict__ sd,
    unsigned short* __restrict__ wgt, unsigned short* __restrict__ wut,
    unsigned short* __restrict__ wdt)
{
    int bx = blockIdx.x;
    int m = bx >> 8;                // 0..26
    int tile = bx & 255;
    int ty = tile >> 4, tx = tile & 15;
    int set = m / 9, e = m % 9;
    const float* src; unsigned short* dst;
    if (set == 0)      { src = (e < 8) ? wg + (size_t)e*1048576 : sg; dst = wgt + (size_t)e*1048576; }
    else if (set == 1) { src = (e < 8) ? wu + (size_t)e*1048576 : su; dst = wut + (size_t)e*1048576; }
    else               { src = (e < 8) ? wd + (size_t)e*1048576 : sd; dst = wdt + (size_t)e*1048576; }

    __shared__ __align__(16) unsigned short ts[64 * 80];
    int t = threadIdx.x;
    int rT0 = ty * 64, cT0 = tx * 64;
    #pragma unroll
    for (int i = 0; i < 16; i++) {
        int lin = t + i * 256;
        int mr = lin >> 6, mc = lin & 63;
        float v = src[(size_t)(cT0 + mr) * 1024 + rT0 + mc];
        ts[mc * 80 + mr] = f2bf(v);
    }
    __syncthreads();
    #pragma unroll
    for (int i = 0; i < 2; i++) {
        int r = (t >> 3) + i * 32;
        int c0 = (t & 7) * 8;
        *(u16x8*)&dst[(size_t)(rT0 + r) * 1024 + cT0 + c0] = *(u16x8*)&ts[r * 80 + c0];
    }
}

// ---------------------------------------------------------------- router
__global__ __launch_bounds__(256) void k_router(
    const float* __restrict__ x, const float* __restrict__ rw,
    int* __restrict__ tk_i, float* __restrict__ tk_w)
{
    int wid = threadIdx.x >> 6, lane = threadIdx.x & 63;
    int n = blockIdx.x * 4 + wid;
    const float* xr = x + (size_t)n * D_DIM;
    float acc[8] = {0,0,0,0,0,0,0,0};
    #pragma unroll
    for (int it = 0; it < 16; it++) {
        int d = it * 64 + lane;
        float xv = xr[d];
        f4 r0 = *(const f4*)(rw + (size_t)d * 8);
        f4 r1 = *(const f4*)(rw + (size_t)d * 8 + 4);
        acc[0] += xv * r0[0]; acc[1] += xv * r0[1]; acc[2] += xv * r0[2]; acc[3] += xv * r0[3];
        acc[4] += xv * r1[0]; acc[5] += xv * r1[1]; acc[6] += xv * r1[2]; acc[7] += xv * r1[3];
    }
    #pragma unroll
    for (int e = 0; e < 8; e++)
        for (int off = 32; off; off >>= 1)
            acc[e] += __shfl_xor(acc[e], off, 64);
    if (lane == 0) {
        float mx = acc[0];
        for (int e = 1; e < 8; e++) mx = fmaxf(mx, acc[e]);
        float p[8], s = 0.f;
        for (int e = 0; e < 8; e++) { p[e] = expf(acc[e] - mx); s += p[e]; }
        int i0 = 0;
        for (int e = 1; e < 8; e++) if (p[e] > p[i0]) i0 = e;
        int i1 = (i0 == 0) ? 1 : 0;
        for (int e = 0; e < 8; e++) if (e != i0 && p[e] > p[i1]) i1 = e;
        float p0 = p[i0] / s, p1 = p[i1] / s;
        float rs = p0 + p1 + 1e-9f;
        tk_i[2*n] = i0;  tk_i[2*n+1] = i1;
        tk_w[2*n] = p0 / rs;  tk_w[2*n+1] = p1 / rs;
    }
}

__global__ __launch_bounds__(256) void k_prefill(int* __restrict__ row_token)
{
    int i = blockIdx.x * 256 + threadIdx.x;
    row_token[i] = -1;
}

// --------------------------------- count + offsets + scatter, ONE block, 0 atomics
__global__ __launch_bounds__(1024) void k_count_scatter(
    const int* __restrict__ tk_i, const float* __restrict__ tk_w,
    int* __restrict__ meta,
    int* __restrict__ row_token, int* __restrict__ row_expert,
    int* __restrict__ tok_pos)
{
    __shared__ int cnt[1024 * 9];   // [thread][expert], stride 9 to spread banks
    __shared__ int tot[8];
    __shared__ int off[9];
    const int t = threadIdx.x;
    const int lane = t & 63;
    const int wid = t >> 6;         // 0..15

    #pragma unroll
    for (int e = 0; e < 8; e++) cnt[t * 9 + e] = 0;
    __syncthreads();

    // phase 1: per-thread histogram of its 8 tokens (16 entries)
    #pragma unroll
    for (int j = 0; j < 8; j++) {
        int n = t * 8 + j;
        cnt[t * 9 + tk_i[2 * n]]++;
        cnt[t * 9 + tk_i[2 * n + 1]]++;
    }
    __syncthreads();

    // phase 2: wave e (e<8) computes exclusive prefix over 1024 threads for expert e
    if (wid < 8) {
        const int e = wid;
        int carry = 0;
        for (int c = 0; c < 16; c++) {
            int i = c * 64 + lane;
            int v = cnt[i * 9 + e];
            int s = v;
            #pragma unroll
            for (int d = 1; d < 64; d <<= 1) {
                int u = __shfl_up(s, d, 64);
                if (lane >= d) s += u;
            }
            cnt[i * 9 + e] = s - v + carry;   // exclusive base for thread i
            carry += __shfl(s, 63, 64);
        }
        if (lane == 0) tot[e] = carry;
    }
    __syncthreads();

    if (t == 0) {
        int acc = 0;
        #pragma unroll
        for (int e = 0; e < 8; e++) {
            off[e] = acc;
            meta[MO + e] = acc;
            acc += ((tot[e] + 255) >> 8) << 8;   // pad to BM=256
        }
        off[8] = acc;
        meta[MO + 8] = acc;
        meta[MT] = acc + N_TOK;
    }
    __syncthreads();

    // phase 3: deterministic scatter (cnt[t][e] now = running position base)
    #pragma unroll
    for (int j = 0; j < 8; j++) {
        int n = t * 8 + j;
        #pragma unroll
        for (int k = 0; k < 2; k++) {
            int e = tk_i[2 * n + k];
            int pos = off[e] + cnt[t * 9 + e];
            cnt[t * 9 + e] = cnt[t * 9 + e] + 1;
            row_token[pos] = n; row_expert[pos] = e;
            tok_pos[2 * n + k] = pos;
        }
        int ps = off[8] + n;
        row_token[ps] = n; row_expert[ps] = 8;
    }
}

// ----------------------------------------------- GEMM1: gate+up, silu*mul -> h
// 512 threads, BM=256 x BN=128, double-buffered LDS (128KB), counted vmcnt.
__global__ __launch_bounds__(512, 2) void k_gemm1(
    const unsigned short* __restrict__ xb,
    const unsigned short* __restrict__ wgt,
    const unsigned short* __restrict__ wut,
    const int* __restrict__ row_token,
    const int* __restrict__ row_expert,
    const int* __restrict__ meta,
    unsigned short* __restrict__ h)
{
    const int total = meta[MT];
    // chunked XCD swizzle (grid 832 = 8*104)
    const int orig = blockIdx.x;
    const int bid = (orig & 7) * 104 + (orig >> 3);
    const int rt = bid >> 3, ct = bid & 7;
    const int row0 = rt * BM;
    if (row0 >= total) return;
    const int e = row_expert[row0];

    __shared__ __align__(16) unsigned short sA[2 * BM * BK];   // 64KB
    __shared__ __align__(16) unsigned short sBg[2 * BN * BK];  // 32KB
    __shared__ __align__(16) unsigned short sBu[2 * BN * BK];  // 32KB

    const int t = threadIdx.x;            // 0..511
    const int lane = t & 63;
    const int wid = t >> 6;               // 0..7
    const int wr = wid >> 1, wc = wid & 1;

    const unsigned short* asrc[4];
    #pragma unroll
    for (int i = 0; i < 4; i++) {
        int slot = t + i * 512;           // 0..2047
        int row = slot >> 3;              // 0..255
        int cg  = (slot & 7) ^ (row & 7);
        int tok = row_token[row0 + row];
        if (tok < 0) tok = 0;
        asrc[i] = xb + (size_t)tok * D_DIM + cg * 8;
    }
    const unsigned short* bsrcg[2];
    const unsigned short* bsrcu[2];
    #pragma unroll
    for (int i = 0; i < 2; i++) {
        int slot = t + i * 512;           // 0..1023
        int row = slot >> 3;              // 0..127
        int cg  = (slot & 7) ^ (row & 7);
        size_t off = ((size_t)e * F_DIM + ct * BN + row) * D_DIM + cg * 8;
        bsrcg[i] = wgt + off;
        bsrcu[i] = wut + off;
    }

    f32x4 accg[4][4] = {}, accu[4][4] = {};

#define STAGE1(bb, k0) do { \
    unsigned short* dA  = &sA[(bb) * (BM * BK)]; \
    unsigned short* dBg = &sBg[(bb) * (BN * BK)]; \
    unsigned short* dBu = &sBu[(bb) * (BN * BK)]; \
    _Pragma("unroll") \
    for (int i_ = 0; i_ < 4; i_++) GLDS(asrc[i_] + (k0), &dA[(t + i_ * 512) * 8]); \
    _Pragma("unroll") \
    for (int i_ = 0; i_ < 2; i_++) { \
        GLDS(bsrcg[i_] + (k0), &dBg[(t + i_ * 512) * 8]); \
        GLDS(bsrcu[i_] + (k0), &dBu[(t + i_ * 512) * 8]); \
    } } while (0)

#define COMPUTE1(bb) do { \
    const unsigned short* pA  = &sA[(bb) * (BM * BK)]; \
    const unsigned short* pBg = &sBg[(bb) * (BN * BK)]; \
    const unsigned short* pBu = &sBu[(bb) * (BN * BK)]; \
    _Pragma("unroll") \
    for (int kk = 0; kk < BK; kk += 32) { \
        const int koff = kk + (lane >> 4) * 8; \
        s16x8 a_[4], bg_[4], bu_[4]; \
        _Pragma("unroll") \
        for (int m_ = 0; m_ < 4; m_++) { \
            int row = wr * 64 + m_ * 16 + (lane & 15); \
            a_[m_] = *(const s16x8*)&pA[RSWZ(row, row * BK + koff)]; } \
        _Pragma("unroll") \
        for (int n_ = 0; n_ < 4; n_++) { \
            int row = wc * 64 + n_ * 16 + (lane & 15); \
            bg_[n_] = *(const s16x8*)&pBg[RSWZ(row, row * BK + koff)]; \
            bu_[n_] = *(const s16x8*)&pBu[RSWZ(row, row * BK + koff)]; } \
        _Pragma("unroll") \
        for (int m_ = 0; m_ < 4; m_++) \
            _Pragma("unroll") \
            for (int n_ = 0; n_ < 4; n_++) { \
                accg[m_][n_] = __builtin_amdgcn_mfma_f32_16x16x32_bf16(a_[m_], bg_[n_], accg[m_][n_], 0, 0, 0); \
                accu[m_][n_] = __builtin_amdgcn_mfma_f32_16x16x32_bf16(a_[m_], bu_[n_], accu[m_][n_], 0, 0, 0); } \
    } } while (0)

    STAGE1(0, 0);
    int cur = 0;
    for (int k0 = 0; k0 < D_DIM - BK; k0 += BK) {
        STAGE1(cur ^ 1, k0 + BK);
        asm volatile("s_waitcnt vmcnt(8)" ::: "memory");
        __builtin_amdgcn_s_barrier();
        __builtin_amdgcn_s_setprio(1);
        COMPUTE1(cur);
        __builtin_amdgcn_s_setprio(0);
        asm volatile("" ::: "memory");
        __builtin_amdgcn_s_barrier();
        cur ^= 1;
    }
    asm volatile("s_waitcnt vmcnt(0)" ::: "memory");
    __builtin_amdgcn_s_barrier();
    __builtin_amdgcn_s_setprio(1);
    COMPUTE1(cur);
    __builtin_amdgcn_s_setprio(0);

    #pragma unroll
    for (int m = 0; m < 4; m++)
        #pragma unroll
        for (int r = 0; r < 4; r++) {
            int grow = row0 + wr * 64 + m * 16 + (lane >> 4) * 4 + r;
            unsigned short* hrow = h + (size_t)grow * F_DIM + ct * BN + wc * 64 + (lane & 15);
            #pragma unroll
            for (int n = 0; n < 4; n++) {
                float g = accg[m][n][r], u = accu[m][n][r];
                float sv = g / (1.f + __expf(-g));
                hrow[n * 16] = f2bf(sv * u);
            }
        }
#undef STAGE1
#undef COMPUTE1
}

// ----------------------------------------------- GEMM2: down -> eo (routed, bf16)
//                                                        -> out (shared, f32)
// 512 threads, 256x256 tile, double-buffered LDS (128KB), NO atomics.
__global__ __launch_bounds__(512, 2) void k_gemm2(
    const unsigned short* __restrict__ h,
    const unsigned short* __restrict__ wdt,
    const int* __restrict__ row_expert,
    const int* __restrict__ meta,
    unsigned short* __restrict__ eo,
    float* __restrict__ out)
{
    const int total = meta[MT];
    const int off8 = meta[MO + 8];
    // chunked XCD swizzle (grid 416 = 8*52)
    const int orig = blockIdx.x;
    const int bid = (orig & 7) * 52 + (orig >> 3);
    const int rt = bid >> 2, ct = bid & 3;
    const int row0 = rt * BM;
    if (row0 >= total) return;
    const int e = row_expert[row0];

    __shared__ __align__(16) unsigned short sA[2 * BM * BK];   // 64KB
    __shared__ __align__(16) unsigned short sB[2 * BN2 * BK];  // 64KB

    const int t = threadIdx.x;
    const int lane = t & 63;
    const int wid = t >> 6;               // 0..7
    const int wr = wid >> 2, wc = wid & 3; // 2 x 4 waves; per wave 128x64 out

    const unsigned short* asrc[4];
    #pragma unroll
    for (int i = 0; i < 4; i++) {
        int slot = t + i * 512;           // 0..2047
        int row = slot >> 3;              // 0..255
        int cg  = (slot & 7) ^ (row & 7);
        asrc[i] = h + (size_t)(row0 + row) * F_DIM + cg * 8;
    }
    const unsigned short* bsrc[4];
    #pragma unroll
    for (int i = 0; i < 4; i++) {
        int slot = t + i * 512;
        int row = slot >> 3;              // 0..255
        int cg  = (slot & 7) ^ (row & 7);
        bsrc[i] = wdt + ((size_t)e * D_DIM + ct * BN2 + row) * F_DIM + cg * 8;
    }

    f32x4 acc[8][4] = {};

#define STAGE2(bb, k0) do { \
    unsigned short* dA = &sA[(bb) * (BM * BK)]; \
    unsigned short* dB = &sB[(bb) * (BN2 * BK)]; \
    _Pragma("unroll") \
    for (int i_ = 0; i_ < 4; i_++) GLDS(asrc[i_] + (k0), &dA[(t + i_ * 512) * 8]); \
    _Pragma("unroll") \
    for (int i_ = 0; i_ < 4; i_++) GLDS(bsrc[i_] + (k0), &dB[(t + i_ * 512) * 8]); \
    } while (0)

#define COMPUTE2(bb) do { \
    const unsigned short* pA = &sA[(bb) * (BM * BK)]; \
    const unsigned short* pB = &sB[(bb) * (BN2 * BK)]; \
    _Pragma("unroll") \
    for (int kk = 0; kk < BK; kk += 32) { \
        const int koff = kk + (lane >> 4) * 8; \
        s16x8 a_[8], b_[4]; \
        _Pragma("unroll") \
        for (int m_ = 0; m_ < 8; m_++) { \
            int row = wr * 128 + m_ * 16 + (lane & 15); \
            a_[m_] = *(const s16x8*)&pA[RSWZ(row, row * BK + koff)]; } \
        _Pragma("unroll") \
        for (int n_ = 0; n_ < 4; n_++) { \
            int row = wc * 64 + n_ * 16 + (lane & 15); \
            b_[n_] = *(const s16x8*)&pB[RSWZ(row, row * BK + koff)]; } \
        _Pragma("unroll") \
        for (int m_ = 0; m_ < 8; m_++) \
            _Pragma("unroll") \
            for (int n_ = 0; n_ < 4; n_++) \
                acc[m_][n_] = __builtin_amdgcn_mfma_f32_16x16x32_bf16(a_[m_], b_[n_], acc[m_][n_], 0, 0, 0); \
    } } while (0)

    STAGE2(0, 0);
    int cur = 0;
    for (int k0 = 0; k0 < F_DIM - BK; k0 += BK) {
        STAGE2(cur ^ 1, k0 + BK);
        asm volatile("s_waitcnt vmcnt(8)" ::: "memory");
        __builtin_amdgcn_s_barrier();
        __builtin_amdgcn_s_setprio(1);
        COMPUTE2(cur);
        __builtin_amdgcn_s_setprio(0);
        asm volatile("" ::: "memory");
        __builtin_amdgcn_s_barrier();
        cur ^= 1;
    }
    asm volatile("s_waitcnt vmcnt(0)" ::: "memory");
    __builtin_amdgcn_s_barrier();
    __builtin_amdgcn_s_setprio(1);
    COMPUTE2(cur);
    __builtin_amdgcn_s_setprio(0);

    if (e < 8) {
        // routed: plain bf16 stores into eo[row][D]
        #pragma unroll
        for (int m = 0; m < 8; m++)
            #pragma unroll
            for (int r = 0; r < 4; r++) {
                int grow = row0 + wr * 128 + m * 16 + (lane >> 4) * 4 + r;
                unsigned short* erow = eo + (size_t)grow * D_DIM + ct * BN2 + wc * 64 + (lane & 15);
                #pragma unroll
                for (int n = 0; n < 4; n++)
                    erow[n * 16] = f2bf(acc[m][n][r]);
            }
    } else {
        // shared expert: each token appears exactly once -> direct f32 store
        #pragma unroll
        for (int m = 0; m < 8; m++)
            #pragma unroll
            for (int r = 0; r < 4; r++) {
                int grow = row0 + wr * 128 + m * 16 + (lane >> 4) * 4 + r;
                int tok = grow - off8;
                float* orow = out + (size_t)tok * D_DIM + ct * BN2 + wc * 64 + (lane & 15);
                #pragma unroll
                for (int n = 0; n < 4; n++)
                    orow[n * 16] = acc[m][n][r];
            }
    }
#undef STAGE2
#undef COMPUTE2
}

// ---------------------------------------- combine: out += w0*eo[p0] + w1*eo[p1]
__global__ __launch_bounds__(256) void k_combine(
    const unsigned short* __restrict__ eo,
    const int* __restrict__ tok_pos, const float* __restrict__ tk_w,
    float* __restrict__ out)
{
    const int t = threadIdx.x;
    const int n = blockIdx.x * 2 + (t >> 7);
    const int c0 = (t & 127) * 8;
    const int p0 = tok_pos[2 * n], p1 = tok_pos[2 * n + 1];
    const float w0 = tk_w[2 * n], w1 = tk_w[2 * n + 1];
    u16x8 a = *(const u16x8*)&eo[(size_t)p0 * D_DIM + c0];
    u16x8 b = *(const u16x8*)&eo[(size_t)p1 * D_DIM + c0];
    float* orow = out + (size_t)n * D_DIM + c0;
    f4 o0 = *(f4*)orow, o1 = *(f4*)(orow + 4);
    #pragma unroll
    for (int j = 0; j < 4; j++) {
        o0[j] += w0 * bf2f(a[j])     + w1 * bf2f(b[j]);
        o1[j] += w0 * bf2f(a[4 + j]) + w1 * bf2f(b[4 + j]);
    }
    *(f4*)orow = o0;
    *(f4*)(orow + 4) = o1;
}

// ---------------------------------------------------------------- launch
extern "C" void kernel_launch(void* const* d_in, const int* in_sizes, int n_in,
                              void* d_out, int out_size, void* d_ws, size_t ws_size,
                              hipStream_t stream)
{
    const float* x  = (const float*)d_in[0];
    const float* rw = (const float*)d_in[1];
    const float* sg = (const float*)d_in[2];
    const float* su = (const float*)d_in[3];
    const float* sd = (const float*)d_in[4];
    const float* wg = (const float*)d_in[5];
    const float* wu = (const float*)d_in[6];
    const float* wd = (const float*)d_in[7];
    float* out = (float*)d_out;

    char* p = (char*)d_ws;
    unsigned short* xb  = (unsigned short*)p; p += (size_t)N_TOK * D_DIM * 2;
    unsigned short* wgt = (unsigned short*)p; p += (size_t)NESH * D_DIM * F_DIM * 2;
    unsigned short* wut = (unsigned short*)p; p += (size_t)NESH * D_DIM * F_DIM * 2;
    unsigned short* wdt = (unsigned short*)p; p += (size_t)NESH * D_DIM * F_DIM * 2;
    unsigned short* h   = (unsigned short*)p; p += (size_t)MAX_ROWS * F_DIM * 2;
    int*   row_token  = (int*)p;   p += (size_t)MAX_ROWS * 4;
    int*   row_expert = (int*)p;   p += (size_t)MAX_ROWS * 4;
    int*   tok_pos = (int*)p;      p += (size_t)N_TOK * 2 * 4;
    int*   tk_i = (int*)p;         p += (size_t)N_TOK * 2 * 4;
    float* tk_w = (float*)p;       p += (size_t)N_TOK * 2 * 4;
    int*   meta = (int*)p;         p += 1024;
    if ((size_t)(p - (char*)d_ws) > ws_size) return;

    // eo (routed down-proj output, bf16, MAX_RTD x D = 37.75 MB) ALIASES wgt+wut:
    // wgt/wut are dead after k_gemm1 and rewritten by k_transpose next call.
    unsigned short* eo = wgt;   // MAX_RTD*D*2 = 2 * NESH*D*F*2 exactly

    k_convert_x<<<N_TOK * D_DIM / 8 / 256, 256, 0, stream>>>(x, xb);
    k_transpose<<<27 * 256, 256, 0, stream>>>(wg, wu, wd, sg, su, sd, wgt, wut, wdt);
    k_router<<<N_TOK / 4, 256, 0, stream>>>(x, rw, tk_i, tk_w);
    k_prefill<<<MAX_ROWS / 256, 256, 0, stream>>>(row_token);
    k_count_scatter<<<1, 1024, 0, stream>>>(tk_i, tk_w, meta, row_token, row_expert, tok_pos);
    k_gemm1<<<(MAX_ROWS / BM) * 8, 512, 0, stream>>>(xb, wgt, wut, row_token, row_expert, meta, h);
    k_gemm2<<<(MAX_ROWS / BM) * 4, 512, 0, stream>>>(h, wdt, row_expert, meta, eo, out);
    k_combine<<<N_TOK / 2, 256, 0, stream>>>(eo, tok_pos, tk_w, out);
}